// Round 4
// baseline (1345.578 us; speedup 1.0000x reference)
//
#include <hip/hip_runtime.h>
#include <math.h>

// ---------------------------------------------------------------------------
// EdgeGAT R4:
//  - Aggregation (layers 1,2) restructured as channel-sliced SpMM: 8 slices of
//    32 channels, slice = blockIdx.x % 8 -> XCD round-robin pinning. Each
//    XCD's gather working set = 3.2 MB h-slice + 0.8 MB ls -> L2-resident
//    (R3 showed agg bound by L2-miss path: FETCH 398 MB @ 3.3 TB/s).
//  - psum_kernel precomputes 1/(sum p + eps) per (node,head), lane-parallel.
//  - Binned CSR build, bf16 h, global-lsmax softmax bound as in R3.
// ---------------------------------------------------------------------------

#define FIN 128
#define HID 64
#define BIN_SHIFT 8   // 256 nodes per bin; requires N <= 65536

__device__ __forceinline__ unsigned f2bfbits(float f) {
    unsigned u = __float_as_uint(f);
    return (u + 0x7fffu + ((u >> 16) & 1u)) >> 16;  // RNE
}
__device__ __forceinline__ float bf_lo(unsigned w) { return __uint_as_float(w << 16); }
__device__ __forceinline__ float bf_hi(unsigned w) { return __uint_as_float(w & 0xffff0000u); }
__device__ __forceinline__ float bf1(unsigned short s) { return __uint_as_float(((unsigned)s) << 16); }

// monotone float<->uint encoding for atomicMax on floats
__device__ __forceinline__ unsigned fenc(float f) {
    unsigned b = __float_as_uint(f);
    return (b & 0x80000000u) ? ~b : (b | 0x80000000u);
}
__device__ __forceinline__ float fdec(unsigned k) {
    unsigned b = (k & 0x80000000u) ? (k ^ 0x80000000u) : ~k;
    return __uint_as_float(b);
}

// ---------------- binned CSR build ----------------

__global__ __launch_bounds__(256) void bincount_kernel(const int* __restrict__ ei,
                                                       int* __restrict__ bincnt,
                                                       int E, int Etot) {
    __shared__ int h[256];
    int t = threadIdx.x;
    h[t] = 0;
    __syncthreads();
    int base = blockIdx.x * 4096;
    #pragma unroll
    for (int i = 0; i < 16; ++i) {
        int e = base + i * 256 + t;
        if (e < Etot) {
            int d = (e < E) ? ei[E + e] : (e - E);
            atomicAdd(&h[d >> BIN_SHIFT], 1);
        }
    }
    __syncthreads();
    if (h[t]) atomicAdd(&bincnt[t], h[t]);
}

__global__ void scanbins_kernel(const int* __restrict__ bincnt, int* __restrict__ binptr,
                                int* __restrict__ bincur, int NB, int Etot) {
    __shared__ int buf[256];
    int t = threadIdx.x;  // 256
    int v = (t < NB) ? bincnt[t] : 0;
    buf[t] = v;
    __syncthreads();
    for (int o = 1; o < 256; o <<= 1) {
        int y = (t >= o) ? buf[t - o] : 0;
        __syncthreads();
        buf[t] += y;
        __syncthreads();
    }
    int excl = buf[t] - v;
    if (t < NB) {
        binptr[t] = excl;
        bincur[t] = excl;
    }
    if (t == 0) binptr[NB] = Etot;
}

__global__ __launch_bounds__(256) void binscatter_kernel(const int* __restrict__ ei,
                                                         int* __restrict__ bincur,
                                                         int2* __restrict__ binned,
                                                         int E, int Etot) {
    __shared__ int h[256];
    __shared__ int gb[256];
    int t = threadIdx.x;
    h[t] = 0;
    __syncthreads();
    int base = blockIdx.x * 4096;
    #pragma unroll
    for (int i = 0; i < 16; ++i) {
        int e = base + i * 256 + t;
        if (e < Etot) {
            int d = (e < E) ? ei[E + e] : (e - E);
            atomicAdd(&h[d >> BIN_SHIFT], 1);
        }
    }
    __syncthreads();
    int cnt = h[t];
    if (cnt) gb[t] = atomicAdd(&bincur[t], cnt);
    __syncthreads();
    h[t] = 0;
    __syncthreads();
    #pragma unroll
    for (int i = 0; i < 16; ++i) {
        int e = base + i * 256 + t;
        if (e < Etot) {
            int s, d;
            if (e < E) { s = ei[e]; d = ei[E + e]; }
            else       { s = e - E; d = e - E; }
            int b = d >> BIN_SHIFT;
            int pos = gb[b] + atomicAdd(&h[b], 1);
            binned[pos] = make_int2(s, d);
        }
    }
}

__global__ __launch_bounds__(256) void bincsr_kernel(const int2* __restrict__ binned,
                                                     const int* __restrict__ binptr,
                                                     int* __restrict__ row_ptr,
                                                     int* __restrict__ col,
                                                     int N, int Etot) {
    __shared__ int h[256];
    __shared__ int cur[256];
    __shared__ int wsum[4];
    int b = blockIdx.x;
    int t = threadIdx.x;
    int lo = b << BIN_SHIFT;
    h[t] = 0;
    __syncthreads();
    int ebeg = binptr[b], eend = binptr[b + 1];
    for (int i = ebeg + t; i < eend; i += 256) atomicAdd(&h[binned[i].y - lo], 1);
    __syncthreads();
    int v = h[t];
    int lane = t & 63, w = t >> 6;
    int x = v;
    #pragma unroll
    for (int o = 1; o < 64; o <<= 1) {
        int y = __shfl_up(x, o);
        if (lane >= o) x += y;
    }
    if (lane == 63) wsum[w] = x;
    __syncthreads();
    int off = 0;
    #pragma unroll
    for (int i = 0; i < 4; ++i) off += (i < w) ? wsum[i] : 0;
    int excl = ebeg + off + x - v;
    int node = lo + t;
    if (node < N) row_ptr[node] = excl;
    cur[t] = excl;
    if (b == 0 && t == 0) row_ptr[N] = Etot;
    __syncthreads();
    for (int i = ebeg + t; i < eend; i += 256) {
        int2 sd = binned[i];
        int pos = atomicAdd(&cur[sd.y - lo], 1);
        col[pos] = sd.x;
    }
}

// ---------------- GEMM: Yb[N,M](bf16) = (X*scale+shift)[N,K] @ W[K,M] --------

__global__ __launch_bounds__(256) void gemm_kernel(
    const float* __restrict__ X, const float* __restrict__ W,
    unsigned short* __restrict__ Yb, int Nrows, int K, int M,
    const float* __restrict__ scale, const float* __restrict__ shift) {
    __shared__ __align__(16) float As[32][68];
    __shared__ __align__(16) float Bs[32][68];
    const int t = threadIdx.x;
    const int row0 = blockIdx.x * 64;
    const int c0 = blockIdx.y * 64;
    const int tm = t >> 4, tn = t & 15;
    const int ar = t >> 3, akq = t & 7;
    const int bk = t >> 4, bq = t & 15;
    float acc[4][4] = {};
    for (int k0 = 0; k0 < K; k0 += 32) {
        #pragma unroll
        for (int hh = 0; hh < 2; ++hh) {
            int r = ar + 32 * hh;
            int grow = row0 + r;
            int gk = k0 + akq * 4;
            float4 xv = make_float4(0.f, 0.f, 0.f, 0.f);
            if (grow < Nrows) xv = *(const float4*)(X + (size_t)grow * K + gk);
            if (scale) {
                float4 sc = *(const float4*)(scale + gk);
                float4 sh = *(const float4*)(shift + gk);
                xv.x = fmaf(xv.x, sc.x, sh.x);
                xv.y = fmaf(xv.y, sc.y, sh.y);
                xv.z = fmaf(xv.z, sc.z, sh.z);
                xv.w = fmaf(xv.w, sc.w, sh.w);
            }
            As[akq * 4 + 0][r] = xv.x;
            As[akq * 4 + 1][r] = xv.y;
            As[akq * 4 + 2][r] = xv.z;
            As[akq * 4 + 3][r] = xv.w;
            int kk = bk + 16 * hh;
            *(float4*)&Bs[kk][bq * 4] =
                *(const float4*)(W + (size_t)(k0 + kk) * M + c0 + bq * 4);
        }
        __syncthreads();
        #pragma unroll
        for (int k = 0; k < 32; ++k) {
            float4 a4 = *(const float4*)&As[k][tm * 4];
            float4 b4 = *(const float4*)&Bs[k][tn * 4];
            float av[4] = {a4.x, a4.y, a4.z, a4.w};
            float bv[4] = {b4.x, b4.y, b4.z, b4.w};
            #pragma unroll
            for (int i = 0; i < 4; ++i)
                #pragma unroll
                for (int j = 0; j < 4; ++j)
                    acc[i][j] = fmaf(av[i], bv[j], acc[i][j]);
        }
        __syncthreads();
    }
    #pragma unroll
    for (int i = 0; i < 4; ++i) {
        int grow = row0 + tm * 4 + i;
        if (grow < Nrows) {
            uint2 pk;
            pk.x = f2bfbits(acc[i][0]) | (f2bfbits(acc[i][1]) << 16);
            pk.y = f2bfbits(acc[i][2]) | (f2bfbits(acc[i][3]) << 16);
            *(uint2*)(Yb + (size_t)grow * M + c0 + tn * 4) = pk;
        }
    }
}

// ---------------- attention coefficients + global ls-max ----------------

template <int H>
__global__ __launch_bounds__(256) void attn_coef_kernel(
    const unsigned short* __restrict__ hb, const float* __restrict__ as_,
    const float* __restrict__ ad_, float* __restrict__ ls,
    float* __restrict__ ld, unsigned* __restrict__ lsmax_g, int N, int ngroups) {
    __shared__ unsigned lmax_lds[4];
    int t = threadIdx.x;
    if (t < 4) lmax_lds[t] = 0;
    __syncthreads();
    int lane = t & 63;
    float lmax = -3.0e38f;
    for (int g = blockIdx.x; g < ngroups; g += gridDim.x) {
        int n = g * 4 + (t >> 6);
        if (n >= N) continue;
        if (H == 4) {
            uint2 w = *(const uint2*)(hb + (size_t)n * 256 + lane * 4);
            float h0 = bf_lo(w.x), h1 = bf_hi(w.x), h2 = bf_lo(w.y), h3 = bf_hi(w.y);
            int cg = lane * 4;
            float4 av = *(const float4*)(as_ + cg);
            float4 dv = *(const float4*)(ad_ + cg);
            float su = h0 * av.x + h1 * av.y + h2 * av.z + h3 * av.w;
            float sd = h0 * dv.x + h1 * dv.y + h2 * dv.z + h3 * dv.w;
            #pragma unroll
            for (int o = 1; o < 16; o <<= 1) {
                su += __shfl_xor(su, o);
                sd += __shfl_xor(sd, o);
            }
            if ((lane & 15) == 0) {
                int hd = lane >> 4;
                ls[(size_t)n * 4 + hd] = su;
                ld[(size_t)n * 4 + hd] = sd;
            }
            lmax = fmaxf(lmax, su);
        } else {
            float hv = bf1(hb[(size_t)n * 64 + lane]);
            float su = hv * as_[lane];
            float sd = hv * ad_[lane];
            #pragma unroll
            for (int o = 32; o; o >>= 1) {
                su += __shfl_xor(su, o);
                sd += __shfl_xor(sd, o);
            }
            if (lane == 0) {
                ls[n] = su;
                ld[n] = sd;
            }
            lmax = fmaxf(lmax, su);
        }
    }
    unsigned key = fenc(lmax);
    if (H == 4) {
        if ((lane & 15) == 0) atomicMax(&lmax_lds[lane >> 4], key);
    } else {
        if (lane == 0) atomicMax(&lmax_lds[0], key);
    }
    __syncthreads();
    if (t < H) atomicMax(&lsmax_g[t], lmax_lds[t]);
}

// ---------------- psum: 1/(sum_e p + eps) per (node, head), H=4 -------------
// Lane-parallel over edges (64/iter); identical p math to sliceagg.

__global__ __launch_bounds__(256) void psum_kernel(
    const float* __restrict__ ls, const float* __restrict__ ld,
    const int* __restrict__ row_ptr, const int* __restrict__ col,
    const unsigned* __restrict__ lsmax_g, float* __restrict__ invps, int N) {
    int lane = threadIdx.x & 63;
    int n = blockIdx.x * 4 + (threadIdx.x >> 6);
    if (n >= N) return;
    float4 ldn = *(const float4*)(ld + (size_t)n * 4);
    float m0 = fmaxf(0.f, ldn.x + fdec(lsmax_g[0]));
    float m1 = fmaxf(0.f, ldn.y + fdec(lsmax_g[1]));
    float m2 = fmaxf(0.f, ldn.z + fdec(lsmax_g[2]));
    float m3 = fmaxf(0.f, ldn.w + fdec(lsmax_g[3]));
    int beg = row_ptr[n], end = row_ptr[n + 1];
    float p0 = 0.f, p1 = 0.f, p2 = 0.f, p3 = 0.f;
    for (int el = beg + lane; el < end; el += 64) {
        int s = col[el];
        float4 l4 = *(const float4*)(ls + (size_t)s * 4);
        float lg, lk;
        lg = l4.x + ldn.x; lk = fmaxf(lg, 0.2f * lg); p0 += __expf(lk - m0);
        lg = l4.y + ldn.y; lk = fmaxf(lg, 0.2f * lg); p1 += __expf(lk - m1);
        lg = l4.z + ldn.z; lk = fmaxf(lg, 0.2f * lg); p2 += __expf(lk - m2);
        lg = l4.w + ldn.w; lk = fmaxf(lg, 0.2f * lg); p3 += __expf(lk - m3);
    }
    #pragma unroll
    for (int o = 32; o; o >>= 1) {
        p0 += __shfl_xor(p0, o);
        p1 += __shfl_xor(p1, o);
        p2 += __shfl_xor(p2, o);
        p3 += __shfl_xor(p3, o);
    }
    if (lane == 0) {
        *(float4*)(invps + (size_t)n * 4) =
            make_float4(1.f / (p0 + 1e-16f), 1.f / (p1 + 1e-16f),
                        1.f / (p2 + 1e-16f), 1.f / (p3 + 1e-16f));
    }
}

// ---------------- channel-sliced aggregation (layers 1,2) -------------------
// slice = blockIdx.x % 8 -> XCD round-robin; slice gather set = 3.2 MB (L2).
// Wave per (node, slice): 8 edge-groups x 8 lanes x 4 channels.

__global__ __launch_bounds__(256) void sliceagg_kernel(
    const unsigned short* __restrict__ hb, const float* __restrict__ ls,
    const float* __restrict__ ld, const float* __restrict__ invps,
    const int* __restrict__ row_ptr, const int* __restrict__ col,
    const float* __restrict__ bias, const unsigned* __restrict__ lsmax_g,
    float* __restrict__ out, int N) {
    int t = threadIdx.x;
    int lane = t & 63;
    int sl = blockIdx.x & 7;                 // slice -> XCD (round-robin)
    int n = (blockIdx.x >> 3) * 4 + (t >> 6);
    if (n >= N) return;
    int hd = sl >> 1;                        // head of this 32-ch slice
    int g = lane >> 3;                       // edge sub-slot 0..7
    int li = lane & 7;                       // channel quad 0..7
    float ldn_h = ld[(size_t)n * 4 + hd];
    float m_h = fmaxf(0.f, ldn_h + fdec(lsmax_g[hd]));
    int beg = row_ptr[n], end = row_ptr[n + 1];
    const unsigned short* hsl = hb + sl * 32 + li * 4;
    float a0 = 0.f, a1 = 0.f, a2 = 0.f, a3 = 0.f;
    for (int j = beg + g; j < end; j += 8) {
        int s = col[j];
        float lsv = ls[(size_t)s * 4 + hd];
        float lg = lsv + ldn_h;
        float lk = fmaxf(lg, 0.2f * lg);
        float pv = __expf(lk - m_h);
        uint2 w = *(const uint2*)(hsl + (size_t)s * 256);  // 64B line per edge
        a0 = fmaf(pv, bf_lo(w.x), a0);
        a1 = fmaf(pv, bf_hi(w.x), a1);
        a2 = fmaf(pv, bf_lo(w.y), a2);
        a3 = fmaf(pv, bf_hi(w.y), a3);
    }
    #pragma unroll
    for (int o = 8; o <= 32; o <<= 1) {      // reduce across 8 edge-groups
        a0 += __shfl_xor(a0, o);
        a1 += __shfl_xor(a1, o);
        a2 += __shfl_xor(a2, o);
        a3 += __shfl_xor(a3, o);
    }
    if (lane < 8) {
        float inv = invps[(size_t)n * 4 + hd];
        int c = sl * 32 + lane * 4;
        float4 bv = *(const float4*)(bias + c);
        float4 o;
        o.x = fmaf(a0, inv, bv.x);
        o.y = fmaf(a1, inv, bv.y);
        o.z = fmaf(a2, inv, bv.z);
        o.w = fmaf(a3, inv, bv.w);
        o.x = (o.x > 0.f) ? o.x : expm1f(o.x);
        o.y = (o.y > 0.f) ? o.y : expm1f(o.y);
        o.z = (o.z > 0.f) ? o.z : expm1f(o.z);
        o.w = (o.w > 0.f) ? o.w : expm1f(o.w);
        *(float4*)(out + (size_t)n * 256 + c) = o;
    }
}

// ---------------- layer-3 aggregation (H=1, outputs u,v) --------------------

__global__ __launch_bounds__(256) void agg3_kernel(
    const unsigned short* __restrict__ hb, const float* __restrict__ ls,
    const float* __restrict__ ld, const int* __restrict__ row_ptr,
    const int* __restrict__ col, const float* __restrict__ bias,
    const float* __restrict__ fcW, float* __restrict__ up, float* __restrict__ vp,
    const unsigned* __restrict__ lsmax_g, int N) {
    int lane = threadIdx.x & 63;
    int n = blockIdx.x * 4 + (threadIdx.x >> 6);
    if (n >= N) return;
    int beg = row_ptr[n], end = row_ptr[n + 1];
    float ldn = ld[n];
    float m_h = fmaxf(0.f, ldn + fdec(lsmax_g[0]));
    float psum = 0.f, acc0 = 0.f;
    for (int base = beg; base < end; base += 64) {
        int el = base + lane;
        int s_r = (el < end) ? col[el] : 0;
        int cnt = min(64, end - base);
        for (int j = 0; j < cnt; ++j) {
            int sj = __shfl(s_r, j);
            float lg = ls[sj] + ldn;
            lg = lg >= 0.f ? lg : 0.2f * lg;
            float pv = __expf(lg - m_h);
            psum += pv;
            acc0 = fmaf(pv, bf1(hb[(size_t)sj * 64 + lane]), acc0);
        }
    }
    float inv = 1.f / (psum + 1e-16f);
    float val = fmaf(acc0, inv, bias[lane]);
    float pu = val * fcW[lane];
    float pv2 = val * fcW[64 + lane];
    #pragma unroll
    for (int o = 32; o; o >>= 1) {
        pu += __shfl_xor(pu, o);
        pv2 += __shfl_xor(pv2, o);
    }
    if (lane == 0) {
        up[n] = pu;
        vp[n] = pv2;
    }
}

// ---------------- BN stats + finalize ----------------

__global__ __launch_bounds__(256) void bn_stats_kernel(const float* __restrict__ y,
                                                       float* __restrict__ sums,
                                                       int N) {
    int c = threadIdx.x;
    int r0 = blockIdx.x * 128;
    int rend = min(r0 + 128, N);
    float s = 0.f, s2 = 0.f;
    for (int r = r0; r < rend; ++r) {
        float v = y[(size_t)r * 256 + c];
        s += v;
        s2 += v * v;
    }
    atomicAdd(&sums[c], s);
    atomicAdd(&sums[256 + c], s2);
}

__global__ void bn_finalize_kernel(const float* __restrict__ sums,
                                   const float* __restrict__ g,
                                   const float* __restrict__ b,
                                   float* __restrict__ scale,
                                   float* __restrict__ shift, int N) {
    int c = threadIdx.x;
    float invN = 1.f / (float)N;
    float mu = sums[c] * invN;
    float var = sums[256 + c] * invN - mu * mu;
    float sc = g[c] * rsqrtf(var + 1e-5f);
    scale[c] = sc;
    shift[c] = b[c] - mu * sc;
}

// ---------------- final edge kernel prep + output ----------------

__global__ void prep_kernel(const float* __restrict__ mlpW2,
                            const float* __restrict__ mlpb2,
                            const float* __restrict__ fcW,
                            const float* __restrict__ fcb,
                            float* __restrict__ w2f, float* __restrict__ c2) {
    int j = threadIdx.x;  // 64
    float s = 0.f;
    for (int k = 0; k < 64; ++k) s += mlpW2[j * 64 + k] * fcW[128 + k];
    w2f[j] = s;
    if (j == 0) {
        float c = fcb[0];
        for (int k = 0; k < 64; ++k) c += mlpb2[k] * fcW[128 + k];
        c2[0] = c;
    }
}

__global__ __launch_bounds__(256) void edge_out_kernel(
    const int* __restrict__ ei, const float* __restrict__ ea,
    const float* __restrict__ W1, const float* __restrict__ b1,
    const float* __restrict__ w2f, const float* __restrict__ c2p,
    const float* __restrict__ u, const float* __restrict__ v,
    float* __restrict__ out, int E) {
    __shared__ __align__(16) float W1T[64][16];
    __shared__ float w2fl[64];
    __shared__ float b1l[64];
    int t = threadIdx.x;
    for (int p = t; p < 1024; p += 256) {
        int i = p >> 6, j = p & 63;
        W1T[j][i] = W1[i * 64 + j];
    }
    if (t < 64) {
        w2fl[t] = w2f[t];
        b1l[t] = b1[t];
    }
    __syncthreads();
    int e = blockIdx.x * 256 + t;
    if (e >= E) return;
    int s0 = ei[e];
    int d0 = ei[E + e];
    const float4* ear = (const float4*)(ea + (size_t)e * 16);
    float4 q0 = ear[0], q1 = ear[1], q2 = ear[2], q3 = ear[3];
    float eav[16] = {q0.x, q0.y, q0.z, q0.w, q1.x, q1.y, q1.z, q1.w,
                     q2.x, q2.y, q2.z, q2.w, q3.x, q3.y, q3.z, q3.w};
    float acc = 0.f;
    #pragma unroll 8
    for (int j = 0; j < 64; ++j) {
        const float4* wr = (const float4*)&W1T[j][0];
        float4 w0 = wr[0], w1 = wr[1], w2 = wr[2], w3 = wr[3];
        float s = b1l[j];
        s = fmaf(eav[0], w0.x, s);  s = fmaf(eav[1], w0.y, s);
        s = fmaf(eav[2], w0.z, s);  s = fmaf(eav[3], w0.w, s);
        s = fmaf(eav[4], w1.x, s);  s = fmaf(eav[5], w1.y, s);
        s = fmaf(eav[6], w1.z, s);  s = fmaf(eav[7], w1.w, s);
        s = fmaf(eav[8], w2.x, s);  s = fmaf(eav[9], w2.y, s);
        s = fmaf(eav[10], w2.z, s); s = fmaf(eav[11], w2.w, s);
        s = fmaf(eav[12], w3.x, s); s = fmaf(eav[13], w3.y, s);
        s = fmaf(eav[14], w3.z, s); s = fmaf(eav[15], w3.w, s);
        s = fmaxf(s, 0.f);
        acc = fmaf(s, w2fl[j], acc);
    }
    out[e] = u[s0] + v[d0] + acc + c2p[0];
}

// ---------------- orchestration ----------------

extern "C" void kernel_launch(void* const* d_in, const int* in_sizes, int n_in,
                              void* d_out, int out_size, void* d_ws, size_t ws_size,
                              hipStream_t stream) {
    const float* x     = (const float*)d_in[0];
    const int*   ei    = (const int*)d_in[1];
    const float* ea    = (const float*)d_in[2];
    const float* W1    = (const float*)d_in[3];
    const float* a1s   = (const float*)d_in[4];
    const float* a1d   = (const float*)d_in[5];
    const float* b1    = (const float*)d_in[6];
    const float* W2    = (const float*)d_in[7];
    const float* a2s   = (const float*)d_in[8];
    const float* a2d   = (const float*)d_in[9];
    const float* b2    = (const float*)d_in[10];
    const float* W3    = (const float*)d_in[11];
    const float* a3s   = (const float*)d_in[12];
    const float* a3d   = (const float*)d_in[13];
    const float* b3    = (const float*)d_in[14];
    const float* bn1g  = (const float*)d_in[15];
    const float* bn1b  = (const float*)d_in[16];
    const float* bn2g  = (const float*)d_in[17];
    const float* bn2b  = (const float*)d_in[18];
    const float* mlpW1 = (const float*)d_in[19];
    const float* mlpb1 = (const float*)d_in[20];
    const float* mlpW2 = (const float*)d_in[21];
    const float* mlpb2 = (const float*)d_in[22];
    const float* fcW   = (const float*)d_in[23];
    const float* fcb   = (const float*)d_in[24];
    float* out = (float*)d_out;

    const int N = in_sizes[0] / FIN;     // 50000
    const int E = in_sizes[1] / 2;       // 1600000
    const int Etot = E + N;
    const int NB = (N + 255) >> BIN_SHIFT;  // 196

    // workspace layout
    char* wsb = (char*)d_ws;
    size_t off = 0;
    auto alloc = [&](size_t bytes) {
        void* p = wsb + off;
        off += (bytes + 63) & ~(size_t)63;
        return p;
    };
    unsigned short* hAb = (unsigned short*)alloc((size_t)N * 256 * 2);
    float* hB  = (float*)alloc((size_t)N * 256 * 4);
    unsigned short* h3b = (unsigned short*)alloc((size_t)N * 64 * 2);
    float* lsb = (float*)alloc((size_t)N * 4 * 4);
    float* ldb = (float*)alloc((size_t)N * 4 * 4);
    float* invps = (float*)alloc((size_t)N * 4 * 4);
    int* row_ptr = (int*)alloc((size_t)(N + 1) * 4);
    int* colb    = (int*)alloc((size_t)Etot * 4);
    int2* binned = (int2*)alloc((size_t)Etot * 8);
    int* bincnt  = (int*)alloc(256 * 4 + 12 * 4);  // + lsmax[3][4] zero-init
    unsigned* lsmax1 = (unsigned*)(bincnt + 256);
    unsigned* lsmax2 = lsmax1 + 4;
    unsigned* lsmax3 = lsmax1 + 8;
    int* binptr  = (int*)alloc((size_t)(NB + 1) * 4);
    int* bincur  = (int*)alloc((size_t)NB * 4);
    float* bnsum   = (float*)alloc(512 * 4);
    float* bnscale = (float*)alloc(256 * 4);
    float* bnshift = (float*)alloc(256 * 4);
    float* ub  = (float*)alloc((size_t)N * 4);
    float* vb  = (float*)alloc((size_t)N * 4);
    float* w2f = (float*)alloc(64 * 4);
    float* c2  = (float*)alloc(16 * 4);
    (void)ws_size; (void)n_in; (void)out_size;

    const int nb4 = (N + 3) / 4;
    const int nch = (Etot + 4095) / 4096;

    // ---- binned CSR build ----
    hipMemsetAsync(bincnt, 0, (256 + 12) * sizeof(int), stream);
    bincount_kernel<<<nch, 256, 0, stream>>>(ei, bincnt, E, Etot);
    scanbins_kernel<<<1, 256, 0, stream>>>(bincnt, binptr, bincur, NB, Etot);
    binscatter_kernel<<<nch, 256, 0, stream>>>(ei, bincur, binned, E, Etot);
    bincsr_kernel<<<NB, 256, 0, stream>>>(binned, binptr, row_ptr, colb, N, Etot);

    dim3 gemm_grid((N + 63) / 64, 4);
    dim3 gemm_grid3((N + 63) / 64, 1);

    // ---- layer 1 ----
    gemm_kernel<<<gemm_grid, 256, 0, stream>>>(x, W1, hAb, N, 128, 256, nullptr, nullptr);
    attn_coef_kernel<4><<<2048, 256, 0, stream>>>(hAb, a1s, a1d, lsb, ldb, lsmax1, N, nb4);
    psum_kernel<<<nb4, 256, 0, stream>>>(lsb, ldb, row_ptr, colb, lsmax1, invps, N);
    sliceagg_kernel<<<nb4 * 8, 256, 0, stream>>>(hAb, lsb, ldb, invps, row_ptr, colb,
                                                 b1, lsmax1, hB, N);
    hipMemsetAsync(bnsum, 0, 512 * sizeof(float), stream);
    bn_stats_kernel<<<(N + 127) / 128, 256, 0, stream>>>(hB, bnsum, N);
    bn_finalize_kernel<<<1, 256, 0, stream>>>(bnsum, bn1g, bn1b, bnscale, bnshift, N);

    // ---- layer 2 ----
    gemm_kernel<<<gemm_grid, 256, 0, stream>>>(hB, W2, hAb, N, 256, 256, bnscale, bnshift);
    attn_coef_kernel<4><<<2048, 256, 0, stream>>>(hAb, a2s, a2d, lsb, ldb, lsmax2, N, nb4);
    psum_kernel<<<nb4, 256, 0, stream>>>(lsb, ldb, row_ptr, colb, lsmax2, invps, N);
    sliceagg_kernel<<<nb4 * 8, 256, 0, stream>>>(hAb, lsb, ldb, invps, row_ptr, colb,
                                                 b2, lsmax2, hB, N);
    hipMemsetAsync(bnsum, 0, 512 * sizeof(float), stream);
    bn_stats_kernel<<<(N + 127) / 128, 256, 0, stream>>>(hB, bnsum, N);
    bn_finalize_kernel<<<1, 256, 0, stream>>>(bnsum, bn2g, bn2b, bnscale, bnshift, N);

    // ---- layer 3 ----
    gemm_kernel<<<gemm_grid3, 256, 0, stream>>>(hB, W3, h3b, N, 256, 64, bnscale, bnshift);
    attn_coef_kernel<1><<<2048, 256, 0, stream>>>(h3b, a3s, a3d, lsb, ldb, lsmax3, N, nb4);
    agg3_kernel<<<nb4, 256, 0, stream>>>(h3b, lsb, ldb, row_ptr, colb, b3,
                                         fcW, ub, vb, lsmax3, N);

    // ---- edge output ----
    prep_kernel<<<1, 64, 0, stream>>>(mlpW2, mlpb2, fcW, fcb, w2f, c2);
    edge_out_kernel<<<(E + 255) / 256, 256, 0, stream>>>(ei, ea, mlpW1, mlpb1, w2f, c2,
                                                         ub, vb, out, E);
}

// Round 5
// 950.723 us; speedup vs baseline: 1.4153x; 1.4153x over previous
//
#include <hip/hip_runtime.h>
#include <math.h>

// ---------------------------------------------------------------------------
// EdgeGAT R5: revert R4's sliceagg (XCD-pinning falsified: FETCH rose 398->479).
// Back to R3 one-wave-per-node agg, with:
//  - agg4: inner loop unrolled x4 (4 independent gathers in flight per wave)
//  - agg3: lane-parallel (4 edges x 16 lanes x uint2), exact psum replication
//  - edge_out: 4 edges/thread, W1 row amortized across them (LDS issue /4)
// bf16 h for gather path, binned CSR build, global-lsmax softmax bound.
// ---------------------------------------------------------------------------

#define FIN 128
#define HID 64
#define BIN_SHIFT 8   // 256 nodes per bin; requires N <= 65536

__device__ __forceinline__ unsigned f2bfbits(float f) {
    unsigned u = __float_as_uint(f);
    return (u + 0x7fffu + ((u >> 16) & 1u)) >> 16;  // RNE
}
__device__ __forceinline__ float bf_lo(unsigned w) { return __uint_as_float(w << 16); }
__device__ __forceinline__ float bf_hi(unsigned w) { return __uint_as_float(w & 0xffff0000u); }
__device__ __forceinline__ float bf1(unsigned short s) { return __uint_as_float(((unsigned)s) << 16); }

// monotone float<->uint encoding for atomicMax on floats
__device__ __forceinline__ unsigned fenc(float f) {
    unsigned b = __float_as_uint(f);
    return (b & 0x80000000u) ? ~b : (b | 0x80000000u);
}
__device__ __forceinline__ float fdec(unsigned k) {
    unsigned b = (k & 0x80000000u) ? (k ^ 0x80000000u) : ~k;
    return __uint_as_float(b);
}

// ---------------- binned CSR build ----------------

__global__ __launch_bounds__(256) void bincount_kernel(const int* __restrict__ ei,
                                                       int* __restrict__ bincnt,
                                                       int E, int Etot) {
    __shared__ int h[256];
    int t = threadIdx.x;
    h[t] = 0;
    __syncthreads();
    int base = blockIdx.x * 4096;
    #pragma unroll
    for (int i = 0; i < 16; ++i) {
        int e = base + i * 256 + t;
        if (e < Etot) {
            int d = (e < E) ? ei[E + e] : (e - E);
            atomicAdd(&h[d >> BIN_SHIFT], 1);
        }
    }
    __syncthreads();
    if (h[t]) atomicAdd(&bincnt[t], h[t]);
}

__global__ void scanbins_kernel(const int* __restrict__ bincnt, int* __restrict__ binptr,
                                int* __restrict__ bincur, int NB, int Etot) {
    __shared__ int buf[256];
    int t = threadIdx.x;  // 256
    int v = (t < NB) ? bincnt[t] : 0;
    buf[t] = v;
    __syncthreads();
    for (int o = 1; o < 256; o <<= 1) {
        int y = (t >= o) ? buf[t - o] : 0;
        __syncthreads();
        buf[t] += y;
        __syncthreads();
    }
    int excl = buf[t] - v;
    if (t < NB) {
        binptr[t] = excl;
        bincur[t] = excl;
    }
    if (t == 0) binptr[NB] = Etot;
}

__global__ __launch_bounds__(256) void binscatter_kernel(const int* __restrict__ ei,
                                                         int* __restrict__ bincur,
                                                         int2* __restrict__ binned,
                                                         int E, int Etot) {
    __shared__ int h[256];
    __shared__ int gb[256];
    int t = threadIdx.x;
    h[t] = 0;
    __syncthreads();
    int base = blockIdx.x * 4096;
    #pragma unroll
    for (int i = 0; i < 16; ++i) {
        int e = base + i * 256 + t;
        if (e < Etot) {
            int d = (e < E) ? ei[E + e] : (e - E);
            atomicAdd(&h[d >> BIN_SHIFT], 1);
        }
    }
    __syncthreads();
    int cnt = h[t];
    if (cnt) gb[t] = atomicAdd(&bincur[t], cnt);
    __syncthreads();
    h[t] = 0;
    __syncthreads();
    #pragma unroll
    for (int i = 0; i < 16; ++i) {
        int e = base + i * 256 + t;
        if (e < Etot) {
            int s, d;
            if (e < E) { s = ei[e]; d = ei[E + e]; }
            else       { s = e - E; d = e - E; }
            int b = d >> BIN_SHIFT;
            int pos = gb[b] + atomicAdd(&h[b], 1);
            binned[pos] = make_int2(s, d);
        }
    }
}

__global__ __launch_bounds__(256) void bincsr_kernel(const int2* __restrict__ binned,
                                                     const int* __restrict__ binptr,
                                                     int* __restrict__ row_ptr,
                                                     int* __restrict__ col,
                                                     int N, int Etot) {
    __shared__ int h[256];
    __shared__ int cur[256];
    __shared__ int wsum[4];
    int b = blockIdx.x;
    int t = threadIdx.x;
    int lo = b << BIN_SHIFT;
    h[t] = 0;
    __syncthreads();
    int ebeg = binptr[b], eend = binptr[b + 1];
    for (int i = ebeg + t; i < eend; i += 256) atomicAdd(&h[binned[i].y - lo], 1);
    __syncthreads();
    int v = h[t];
    int lane = t & 63, w = t >> 6;
    int x = v;
    #pragma unroll
    for (int o = 1; o < 64; o <<= 1) {
        int y = __shfl_up(x, o);
        if (lane >= o) x += y;
    }
    if (lane == 63) wsum[w] = x;
    __syncthreads();
    int off = 0;
    #pragma unroll
    for (int i = 0; i < 4; ++i) off += (i < w) ? wsum[i] : 0;
    int excl = ebeg + off + x - v;
    int node = lo + t;
    if (node < N) row_ptr[node] = excl;
    cur[t] = excl;
    if (b == 0 && t == 0) row_ptr[N] = Etot;
    __syncthreads();
    for (int i = ebeg + t; i < eend; i += 256) {
        int2 sd = binned[i];
        int pos = atomicAdd(&cur[sd.y - lo], 1);
        col[pos] = sd.x;
    }
}

// ---------------- GEMM: Yb[N,M](bf16) = (X*scale+shift)[N,K] @ W[K,M] --------

__global__ __launch_bounds__(256) void gemm_kernel(
    const float* __restrict__ X, const float* __restrict__ W,
    unsigned short* __restrict__ Yb, int Nrows, int K, int M,
    const float* __restrict__ scale, const float* __restrict__ shift) {
    __shared__ __align__(16) float As[32][68];
    __shared__ __align__(16) float Bs[32][68];
    const int t = threadIdx.x;
    const int row0 = blockIdx.x * 64;
    const int c0 = blockIdx.y * 64;
    const int tm = t >> 4, tn = t & 15;
    const int ar = t >> 3, akq = t & 7;
    const int bk = t >> 4, bq = t & 15;
    float acc[4][4] = {};
    for (int k0 = 0; k0 < K; k0 += 32) {
        #pragma unroll
        for (int hh = 0; hh < 2; ++hh) {
            int r = ar + 32 * hh;
            int grow = row0 + r;
            int gk = k0 + akq * 4;
            float4 xv = make_float4(0.f, 0.f, 0.f, 0.f);
            if (grow < Nrows) xv = *(const float4*)(X + (size_t)grow * K + gk);
            if (scale) {
                float4 sc = *(const float4*)(scale + gk);
                float4 sh = *(const float4*)(shift + gk);
                xv.x = fmaf(xv.x, sc.x, sh.x);
                xv.y = fmaf(xv.y, sc.y, sh.y);
                xv.z = fmaf(xv.z, sc.z, sh.z);
                xv.w = fmaf(xv.w, sc.w, sh.w);
            }
            As[akq * 4 + 0][r] = xv.x;
            As[akq * 4 + 1][r] = xv.y;
            As[akq * 4 + 2][r] = xv.z;
            As[akq * 4 + 3][r] = xv.w;
            int kk = bk + 16 * hh;
            *(float4*)&Bs[kk][bq * 4] =
                *(const float4*)(W + (size_t)(k0 + kk) * M + c0 + bq * 4);
        }
        __syncthreads();
        #pragma unroll
        for (int k = 0; k < 32; ++k) {
            float4 a4 = *(const float4*)&As[k][tm * 4];
            float4 b4 = *(const float4*)&Bs[k][tn * 4];
            float av[4] = {a4.x, a4.y, a4.z, a4.w};
            float bv[4] = {b4.x, b4.y, b4.z, b4.w};
            #pragma unroll
            for (int i = 0; i < 4; ++i)
                #pragma unroll
                for (int j = 0; j < 4; ++j)
                    acc[i][j] = fmaf(av[i], bv[j], acc[i][j]);
        }
        __syncthreads();
    }
    #pragma unroll
    for (int i = 0; i < 4; ++i) {
        int grow = row0 + tm * 4 + i;
        if (grow < Nrows) {
            uint2 pk;
            pk.x = f2bfbits(acc[i][0]) | (f2bfbits(acc[i][1]) << 16);
            pk.y = f2bfbits(acc[i][2]) | (f2bfbits(acc[i][3]) << 16);
            *(uint2*)(Yb + (size_t)grow * M + c0 + tn * 4) = pk;
        }
    }
}

// ---------------- attention coefficients + global ls-max ----------------

template <int H>
__global__ __launch_bounds__(256) void attn_coef_kernel(
    const unsigned short* __restrict__ hb, const float* __restrict__ as_,
    const float* __restrict__ ad_, float* __restrict__ ls,
    float* __restrict__ ld, unsigned* __restrict__ lsmax_g, int N, int ngroups) {
    __shared__ unsigned lmax_lds[4];
    int t = threadIdx.x;
    if (t < 4) lmax_lds[t] = 0;
    __syncthreads();
    int lane = t & 63;
    float lmax = -3.0e38f;
    for (int g = blockIdx.x; g < ngroups; g += gridDim.x) {
        int n = g * 4 + (t >> 6);
        if (n >= N) continue;
        if (H == 4) {
            uint2 w = *(const uint2*)(hb + (size_t)n * 256 + lane * 4);
            float h0 = bf_lo(w.x), h1 = bf_hi(w.x), h2 = bf_lo(w.y), h3 = bf_hi(w.y);
            int cg = lane * 4;
            float4 av = *(const float4*)(as_ + cg);
            float4 dv = *(const float4*)(ad_ + cg);
            float su = h0 * av.x + h1 * av.y + h2 * av.z + h3 * av.w;
            float sd = h0 * dv.x + h1 * dv.y + h2 * dv.z + h3 * dv.w;
            #pragma unroll
            for (int o = 1; o < 16; o <<= 1) {
                su += __shfl_xor(su, o);
                sd += __shfl_xor(sd, o);
            }
            if ((lane & 15) == 0) {
                int hd = lane >> 4;
                ls[(size_t)n * 4 + hd] = su;
                ld[(size_t)n * 4 + hd] = sd;
            }
            lmax = fmaxf(lmax, su);
        } else {
            float hv = bf1(hb[(size_t)n * 64 + lane]);
            float su = hv * as_[lane];
            float sd = hv * ad_[lane];
            #pragma unroll
            for (int o = 32; o; o >>= 1) {
                su += __shfl_xor(su, o);
                sd += __shfl_xor(sd, o);
            }
            if (lane == 0) {
                ls[n] = su;
                ld[n] = sd;
            }
            lmax = fmaxf(lmax, su);
        }
    }
    unsigned key = fenc(lmax);
    if (H == 4) {
        if ((lane & 15) == 0) atomicMax(&lmax_lds[lane >> 4], key);
    } else {
        if (lane == 0) atomicMax(&lmax_lds[0], key);
    }
    __syncthreads();
    if (t < H) atomicMax(&lsmax_g[t], lmax_lds[t]);
}

// ---------------- layer-1/2 aggregation: one wave per node, unroll x4 -------

__global__ __launch_bounds__(256) void agg4_kernel(
    const unsigned short* __restrict__ hb, const float* __restrict__ ls,
    const float* __restrict__ ld, const int* __restrict__ row_ptr,
    const int* __restrict__ col, const float* __restrict__ bias,
    const unsigned* __restrict__ lsmax_g, float* __restrict__ out, int N) {
    int lane = threadIdx.x & 63;
    int n = blockIdx.x * 4 + (threadIdx.x >> 6);
    if (n >= N) return;
    int beg = row_ptr[n], end = row_ptr[n + 1];
    const int hd = lane >> 4;
    float4 ldn = *(const float4*)(ld + (size_t)n * 4);
    float ldn_h = (hd == 0) ? ldn.x : (hd == 1) ? ldn.y : (hd == 2) ? ldn.z : ldn.w;
    float m_h = fmaxf(0.f, ldn_h + fdec(lsmax_g[hd]));
    const int c0 = lane * 4;
    float psum = 0.f;
    float a0 = 0.f, a1 = 0.f, a2 = 0.f, a3 = 0.f;
    for (int base = beg; base < end; base += 64) {
        int el = base + lane;
        int s_r = (el < end) ? col[el] : 0;
        int cnt = min(64, end - base);
        int j = 0;
        for (; j + 4 <= cnt; j += 4) {
            int s0 = __shfl(s_r, j);
            int s1 = __shfl(s_r, j + 1);
            int s2 = __shfl(s_r, j + 2);
            int s3 = __shfl(s_r, j + 3);
            float l0 = ls[(size_t)s0 * 4 + hd];
            float l1 = ls[(size_t)s1 * 4 + hd];
            float l2 = ls[(size_t)s2 * 4 + hd];
            float l3 = ls[(size_t)s3 * 4 + hd];
            uint2 w0 = *(const uint2*)(hb + (size_t)s0 * 256 + c0);
            uint2 w1 = *(const uint2*)(hb + (size_t)s1 * 256 + c0);
            uint2 w2 = *(const uint2*)(hb + (size_t)s2 * 256 + c0);
            uint2 w3 = *(const uint2*)(hb + (size_t)s3 * 256 + c0);
            float g0 = l0 + ldn_h; g0 = fmaxf(g0, 0.2f * g0);
            float g1 = l1 + ldn_h; g1 = fmaxf(g1, 0.2f * g1);
            float g2 = l2 + ldn_h; g2 = fmaxf(g2, 0.2f * g2);
            float g3 = l3 + ldn_h; g3 = fmaxf(g3, 0.2f * g3);
            float p0 = __expf(g0 - m_h), p1 = __expf(g1 - m_h);
            float p2 = __expf(g2 - m_h), p3 = __expf(g3 - m_h);
            psum += (p0 + p1) + (p2 + p3);
            a0 = fmaf(p0, bf_lo(w0.x), a0); a1 = fmaf(p0, bf_hi(w0.x), a1);
            a2 = fmaf(p0, bf_lo(w0.y), a2); a3 = fmaf(p0, bf_hi(w0.y), a3);
            a0 = fmaf(p1, bf_lo(w1.x), a0); a1 = fmaf(p1, bf_hi(w1.x), a1);
            a2 = fmaf(p1, bf_lo(w1.y), a2); a3 = fmaf(p1, bf_hi(w1.y), a3);
            a0 = fmaf(p2, bf_lo(w2.x), a0); a1 = fmaf(p2, bf_hi(w2.x), a1);
            a2 = fmaf(p2, bf_lo(w2.y), a2); a3 = fmaf(p2, bf_hi(w2.y), a3);
            a0 = fmaf(p3, bf_lo(w3.x), a0); a1 = fmaf(p3, bf_hi(w3.x), a1);
            a2 = fmaf(p3, bf_lo(w3.y), a2); a3 = fmaf(p3, bf_hi(w3.y), a3);
        }
        for (; j < cnt; ++j) {
            int sj = __shfl(s_r, j);
            float lv = ls[(size_t)sj * 4 + hd];
            float gg = lv + ldn_h; gg = fmaxf(gg, 0.2f * gg);
            float pv = __expf(gg - m_h);
            psum += pv;
            uint2 w = *(const uint2*)(hb + (size_t)sj * 256 + c0);
            a0 = fmaf(pv, bf_lo(w.x), a0); a1 = fmaf(pv, bf_hi(w.x), a1);
            a2 = fmaf(pv, bf_lo(w.y), a2); a3 = fmaf(pv, bf_hi(w.y), a3);
        }
    }
    float inv = 1.f / (psum + 1e-16f);
    float4 bv = *(const float4*)(bias + c0);
    float4 o;
    o.x = fmaf(a0, inv, bv.x);
    o.y = fmaf(a1, inv, bv.y);
    o.z = fmaf(a2, inv, bv.z);
    o.w = fmaf(a3, inv, bv.w);
    o.x = (o.x > 0.f) ? o.x : expm1f(o.x);
    o.y = (o.y > 0.f) ? o.y : expm1f(o.y);
    o.z = (o.z > 0.f) ? o.z : expm1f(o.z);
    o.w = (o.w > 0.f) ? o.w : expm1f(o.w);
    *(float4*)(out + (size_t)n * 256 + c0) = o;
}

// ---------------- layer-3 aggregation (H=1): lane-parallel ------------------
// 4 edge-groups x 16 lanes x uint2(4ch). psum replicated 16x within a group
// (power-of-2 exact after butterfly, divided back via *0.0625).

__global__ __launch_bounds__(256) void agg3_kernel(
    const unsigned short* __restrict__ hb, const float* __restrict__ ls,
    const float* __restrict__ ld, const int* __restrict__ row_ptr,
    const int* __restrict__ col, const float* __restrict__ bias,
    const float* __restrict__ fcW, float* __restrict__ up, float* __restrict__ vp,
    const unsigned* __restrict__ lsmax_g, int N) {
    int lane = threadIdx.x & 63;
    int n = blockIdx.x * 4 + (threadIdx.x >> 6);
    if (n >= N) return;
    int beg = row_ptr[n], end = row_ptr[n + 1];
    float ldn = ld[n];
    float m_h = fmaxf(0.f, ldn + fdec(lsmax_g[0]));
    int g = lane >> 4;    // edge group 0..3
    int li = lane & 15;   // channel quad 0..15
    float psum = 0.f;
    float a0 = 0.f, a1 = 0.f, a2 = 0.f, a3 = 0.f;
    for (int j = beg + g; j < end; j += 4) {
        int s = col[j];
        float lg = ls[s] + ldn;
        lg = fmaxf(lg, 0.2f * lg);
        float pv = __expf(lg - m_h);
        psum += pv;
        uint2 w = *(const uint2*)(hb + (size_t)s * 64 + li * 4);
        a0 = fmaf(pv, bf_lo(w.x), a0);
        a1 = fmaf(pv, bf_hi(w.x), a1);
        a2 = fmaf(pv, bf_lo(w.y), a2);
        a3 = fmaf(pv, bf_hi(w.y), a3);
    }
    // reduce across the 4 edge-groups; psum becomes 16x true value (exact)
    #pragma unroll
    for (int o = 16; o <= 32; o <<= 1) {
        psum += __shfl_xor(psum, o);
        a0 += __shfl_xor(a0, o);
        a1 += __shfl_xor(a1, o);
        a2 += __shfl_xor(a2, o);
        a3 += __shfl_xor(a3, o);
    }
    // here psum = sum over all edges (each group's psum replicated across its
    // 16 lanes, but xor16/32 only sums across groups -> counted once). a* hold
    // channel sums for quad li.
    float inv = 1.f / (psum + 1e-16f);
    int c = li * 4;
    float v0 = fmaf(a0, inv, bias[c + 0]);
    float v1 = fmaf(a1, inv, bias[c + 1]);
    float v2 = fmaf(a2, inv, bias[c + 2]);
    float v3 = fmaf(a3, inv, bias[c + 3]);
    float pu = v0 * fcW[c] + v1 * fcW[c + 1] + v2 * fcW[c + 2] + v3 * fcW[c + 3];
    float pv2 = v0 * fcW[64 + c] + v1 * fcW[64 + c + 1] + v2 * fcW[64 + c + 2] +
                v3 * fcW[64 + c + 3];
    #pragma unroll
    for (int o = 1; o <= 8; o <<= 1) {
        pu += __shfl_xor(pu, o);
        pv2 += __shfl_xor(pv2, o);
    }
    if (lane == 0) {
        up[n] = pu;
        vp[n] = pv2;
    }
}

// ---------------- BN stats + finalize ----------------

__global__ __launch_bounds__(256) void bn_stats_kernel(const float* __restrict__ y,
                                                       float* __restrict__ sums,
                                                       int N) {
    int c = threadIdx.x;
    int r0 = blockIdx.x * 128;
    int rend = min(r0 + 128, N);
    float s = 0.f, s2 = 0.f;
    for (int r = r0; r < rend; ++r) {
        float v = y[(size_t)r * 256 + c];
        s += v;
        s2 += v * v;
    }
    atomicAdd(&sums[c], s);
    atomicAdd(&sums[256 + c], s2);
}

__global__ void bn_finalize_kernel(const float* __restrict__ sums,
                                   const float* __restrict__ g,
                                   const float* __restrict__ b,
                                   float* __restrict__ scale,
                                   float* __restrict__ shift, int N) {
    int c = threadIdx.x;
    float invN = 1.f / (float)N;
    float mu = sums[c] * invN;
    float var = sums[256 + c] * invN - mu * mu;
    float sc = g[c] * rsqrtf(var + 1e-5f);
    scale[c] = sc;
    shift[c] = b[c] - mu * sc;
}

// ---------------- final edge kernel prep + output ----------------

__global__ void prep_kernel(const float* __restrict__ mlpW2,
                            const float* __restrict__ mlpb2,
                            const float* __restrict__ fcW,
                            const float* __restrict__ fcb,
                            float* __restrict__ w2f, float* __restrict__ c2) {
    int j = threadIdx.x;  // 64
    float s = 0.f;
    for (int k = 0; k < 64; ++k) s += mlpW2[j * 64 + k] * fcW[128 + k];
    w2f[j] = s;
    if (j == 0) {
        float c = fcb[0];
        for (int k = 0; k < 64; ++k) c += mlpb2[k] * fcW[128 + k];
        c2[0] = c;
    }
}

// 4 edges per thread; W1 row read from LDS once per j, reused across 4 edges.
__global__ __launch_bounds__(256) void edge_out_kernel(
    const int* __restrict__ ei, const float* __restrict__ ea,
    const float* __restrict__ W1, const float* __restrict__ b1,
    const float* __restrict__ w2f, const float* __restrict__ c2p,
    const float* __restrict__ u, const float* __restrict__ v,
    float* __restrict__ out, int E) {
    __shared__ __align__(16) float W1T[64][16];
    __shared__ float w2fl[64];
    __shared__ float b1l[64];
    int t = threadIdx.x;
    for (int p = t; p < 1024; p += 256) {
        int i = p >> 6, j = p & 63;
        W1T[j][i] = W1[i * 64 + j];
    }
    if (t < 64) {
        w2fl[t] = w2f[t];
        b1l[t] = b1[t];
    }
    __syncthreads();
    int base = blockIdx.x * 1024;
    float eav[4][16];
    int sidx[4], didx[4];
    bool ok[4];
    #pragma unroll
    for (int k = 0; k < 4; ++k) {
        int e = base + k * 256 + t;
        ok[k] = e < E;
        int ec = ok[k] ? e : 0;
        sidx[k] = ei[ec];
        didx[k] = ei[E + ec];
        const float4* ear = (const float4*)(ea + (size_t)ec * 16);
        float4 q0 = ear[0], q1 = ear[1], q2 = ear[2], q3 = ear[3];
        eav[k][0] = q0.x;  eav[k][1] = q0.y;  eav[k][2] = q0.z;  eav[k][3] = q0.w;
        eav[k][4] = q1.x;  eav[k][5] = q1.y;  eav[k][6] = q1.z;  eav[k][7] = q1.w;
        eav[k][8] = q2.x;  eav[k][9] = q2.y;  eav[k][10] = q2.z; eav[k][11] = q2.w;
        eav[k][12] = q3.x; eav[k][13] = q3.y; eav[k][14] = q3.z; eav[k][15] = q3.w;
    }
    float acc[4] = {0.f, 0.f, 0.f, 0.f};
    #pragma unroll 4
    for (int j = 0; j < 64; ++j) {
        const float4* wr = (const float4*)&W1T[j][0];
        float4 w0 = wr[0], w1 = wr[1], w2 = wr[2], w3 = wr[3];
        float wrow[16] = {w0.x, w0.y, w0.z, w0.w, w1.x, w1.y, w1.z, w1.w,
                          w2.x, w2.y, w2.z, w2.w, w3.x, w3.y, w3.z, w3.w};
        float bj = b1l[j], wj = w2fl[j];
        #pragma unroll
        for (int k = 0; k < 4; ++k) {
            float s = bj;
            #pragma unroll
            for (int q = 0; q < 16; ++q) s = fmaf(eav[k][q], wrow[q], s);
            s = fmaxf(s, 0.f);
            acc[k] = fmaf(s, wj, acc[k]);
        }
    }
    float cc = c2p[0];
    #pragma unroll
    for (int k = 0; k < 4; ++k) {
        if (ok[k]) {
            int e = base + k * 256 + t;
            out[e] = u[sidx[k]] + v[didx[k]] + acc[k] + cc;
        }
    }
}

// ---------------- orchestration ----------------

extern "C" void kernel_launch(void* const* d_in, const int* in_sizes, int n_in,
                              void* d_out, int out_size, void* d_ws, size_t ws_size,
                              hipStream_t stream) {
    const float* x     = (const float*)d_in[0];
    const int*   ei    = (const int*)d_in[1];
    const float* ea    = (const float*)d_in[2];
    const float* W1    = (const float*)d_in[3];
    const float* a1s   = (const float*)d_in[4];
    const float* a1d   = (const float*)d_in[5];
    const float* b1    = (const float*)d_in[6];
    const float* W2    = (const float*)d_in[7];
    const float* a2s   = (const float*)d_in[8];
    const float* a2d   = (const float*)d_in[9];
    const float* b2    = (const float*)d_in[10];
    const float* W3    = (const float*)d_in[11];
    const float* a3s   = (const float*)d_in[12];
    const float* a3d   = (const float*)d_in[13];
    const float* b3    = (const float*)d_in[14];
    const float* bn1g  = (const float*)d_in[15];
    const float* bn1b  = (const float*)d_in[16];
    const float* bn2g  = (const float*)d_in[17];
    const float* bn2b  = (const float*)d_in[18];
    const float* mlpW1 = (const float*)d_in[19];
    const float* mlpb1 = (const float*)d_in[20];
    const float* mlpW2 = (const float*)d_in[21];
    const float* mlpb2 = (const float*)d_in[22];
    const float* fcW   = (const float*)d_in[23];
    const float* fcb   = (const float*)d_in[24];
    float* out = (float*)d_out;

    const int N = in_sizes[0] / FIN;     // 50000
    const int E = in_sizes[1] / 2;       // 1600000
    const int Etot = E + N;
    const int NB = (N + 255) >> BIN_SHIFT;  // 196

    // workspace layout
    char* wsb = (char*)d_ws;
    size_t off = 0;
    auto alloc = [&](size_t bytes) {
        void* p = wsb + off;
        off += (bytes + 63) & ~(size_t)63;
        return p;
    };
    unsigned short* hAb = (unsigned short*)alloc((size_t)N * 256 * 2);
    float* hB  = (float*)alloc((size_t)N * 256 * 4);
    unsigned short* h3b = (unsigned short*)alloc((size_t)N * 64 * 2);
    float* lsb = (float*)alloc((size_t)N * 4 * 4);
    float* ldb = (float*)alloc((size_t)N * 4 * 4);
    int* row_ptr = (int*)alloc((size_t)(N + 1) * 4);
    int* colb    = (int*)alloc((size_t)Etot * 4);
    int2* binned = (int2*)alloc((size_t)Etot * 8);
    int* bincnt  = (int*)alloc(256 * 4 + 12 * 4);  // + lsmax[3][4] zero-init
    unsigned* lsmax1 = (unsigned*)(bincnt + 256);
    unsigned* lsmax2 = lsmax1 + 4;
    unsigned* lsmax3 = lsmax1 + 8;
    int* binptr  = (int*)alloc((size_t)(NB + 1) * 4);
    int* bincur  = (int*)alloc((size_t)NB * 4);
    float* bnsum   = (float*)alloc(512 * 4);
    float* bnscale = (float*)alloc(256 * 4);
    float* bnshift = (float*)alloc(256 * 4);
    float* ub  = (float*)alloc((size_t)N * 4);
    float* vb  = (float*)alloc((size_t)N * 4);
    float* w2f = (float*)alloc(64 * 4);
    float* c2  = (float*)alloc(16 * 4);
    (void)ws_size; (void)n_in; (void)out_size;

    const int nb4 = (N + 3) / 4;
    const int nch = (Etot + 4095) / 4096;

    // ---- binned CSR build ----
    hipMemsetAsync(bincnt, 0, (256 + 12) * sizeof(int), stream);
    bincount_kernel<<<nch, 256, 0, stream>>>(ei, bincnt, E, Etot);
    scanbins_kernel<<<1, 256, 0, stream>>>(bincnt, binptr, bincur, NB, Etot);
    binscatter_kernel<<<nch, 256, 0, stream>>>(ei, bincur, binned, E, Etot);
    bincsr_kernel<<<NB, 256, 0, stream>>>(binned, binptr, row_ptr, colb, N, Etot);

    dim3 gemm_grid((N + 63) / 64, 4);
    dim3 gemm_grid3((N + 63) / 64, 1);

    // ---- layer 1 ----
    gemm_kernel<<<gemm_grid, 256, 0, stream>>>(x, W1, hAb, N, 128, 256, nullptr, nullptr);
    attn_coef_kernel<4><<<2048, 256, 0, stream>>>(hAb, a1s, a1d, lsb, ldb, lsmax1, N, nb4);
    agg4_kernel<<<nb4, 256, 0, stream>>>(hAb, lsb, ldb, row_ptr, colb, b1, lsmax1, hB, N);
    hipMemsetAsync(bnsum, 0, 512 * sizeof(float), stream);
    bn_stats_kernel<<<(N + 127) / 128, 256, 0, stream>>>(hB, bnsum, N);
    bn_finalize_kernel<<<1, 256, 0, stream>>>(bnsum, bn1g, bn1b, bnscale, bnshift, N);

    // ---- layer 2 ----
    gemm_kernel<<<gemm_grid, 256, 0, stream>>>(hB, W2, hAb, N, 256, 256, bnscale, bnshift);
    attn_coef_kernel<4><<<2048, 256, 0, stream>>>(hAb, a2s, a2d, lsb, ldb, lsmax2, N, nb4);
    agg4_kernel<<<nb4, 256, 0, stream>>>(hAb, lsb, ldb, row_ptr, colb, b2, lsmax2, hB, N);
    hipMemsetAsync(bnsum, 0, 512 * sizeof(float), stream);
    bn_stats_kernel<<<(N + 127) / 128, 256, 0, stream>>>(hB, bnsum, N);
    bn_finalize_kernel<<<1, 256, 0, stream>>>(bnsum, bn2g, bn2b, bnscale, bnshift, N);

    // ---- layer 3 ----
    gemm_kernel<<<gemm_grid3, 256, 0, stream>>>(hB, W3, h3b, N, 256, 64, bnscale, bnshift);
    attn_coef_kernel<1><<<2048, 256, 0, stream>>>(h3b, a3s, a3d, lsb, ldb, lsmax3, N, nb4);
    agg3_kernel<<<nb4, 256, 0, stream>>>(h3b, lsb, ldb, row_ptr, colb, b3,
                                         fcW, ub, vb, lsmax3, N);

    // ---- edge output ----
    prep_kernel<<<1, 64, 0, stream>>>(mlpW2, mlpb2, fcW, fcb, w2f, c2);
    edge_out_kernel<<<(E + 1023) / 1024, 256, 0, stream>>>(ei, ea, mlpW1, mlpb1, w2f, c2,
                                                           ub, vb, out, E);
}

// Round 6
// 865.976 us; speedup vs baseline: 1.5538x; 1.0979x over previous
//
#include <hip/hip_runtime.h>
#include <math.h>

// ---------------------------------------------------------------------------
// EdgeGAT R6:
//  - GEMMs moved to bf16 MFMA (16x16x32), 128x64 block tile, 4 waves.
//    fp32 vector GEMM was the est. ~250-350us hidden mass (11.5 GF @ ~40TF).
//  - agg4 inner loop unroll 4 -> 8 (more gathers in flight; 56% VALUBusy
//    said latency still dominated).
//  - Else unchanged from R5 (binned CSR, global-lsmax softmax, bf16 h).
// ---------------------------------------------------------------------------

#define FIN 128
#define HID 64
#define BIN_SHIFT 8   // 256 nodes per bin; requires N <= 65536

typedef __bf16 bf16x8 __attribute__((ext_vector_type(8)));
typedef float f32x4 __attribute__((ext_vector_type(4)));

__device__ __forceinline__ unsigned f2bfbits(float f) {
    unsigned u = __float_as_uint(f);
    return (u + 0x7fffu + ((u >> 16) & 1u)) >> 16;  // RNE
}
__device__ __forceinline__ float bf_lo(unsigned w) { return __uint_as_float(w << 16); }
__device__ __forceinline__ float bf_hi(unsigned w) { return __uint_as_float(w & 0xffff0000u); }
__device__ __forceinline__ float bf1(unsigned short s) { return __uint_as_float(((unsigned)s) << 16); }

// monotone float<->uint encoding for atomicMax on floats
__device__ __forceinline__ unsigned fenc(float f) {
    unsigned b = __float_as_uint(f);
    return (b & 0x80000000u) ? ~b : (b | 0x80000000u);
}
__device__ __forceinline__ float fdec(unsigned k) {
    unsigned b = (k & 0x80000000u) ? (k ^ 0x80000000u) : ~k;
    return __uint_as_float(b);
}

// ---------------- binned CSR build ----------------

__global__ __launch_bounds__(256) void bincount_kernel(const int* __restrict__ ei,
                                                       int* __restrict__ bincnt,
                                                       int E, int Etot) {
    __shared__ int h[256];
    int t = threadIdx.x;
    h[t] = 0;
    __syncthreads();
    int base = blockIdx.x * 4096;
    #pragma unroll
    for (int i = 0; i < 16; ++i) {
        int e = base + i * 256 + t;
        if (e < Etot) {
            int d = (e < E) ? ei[E + e] : (e - E);
            atomicAdd(&h[d >> BIN_SHIFT], 1);
        }
    }
    __syncthreads();
    if (h[t]) atomicAdd(&bincnt[t], h[t]);
}

__global__ void scanbins_kernel(const int* __restrict__ bincnt, int* __restrict__ binptr,
                                int* __restrict__ bincur, int NB, int Etot) {
    __shared__ int buf[256];
    int t = threadIdx.x;  // 256
    int v = (t < NB) ? bincnt[t] : 0;
    buf[t] = v;
    __syncthreads();
    for (int o = 1; o < 256; o <<= 1) {
        int y = (t >= o) ? buf[t - o] : 0;
        __syncthreads();
        buf[t] += y;
        __syncthreads();
    }
    int excl = buf[t] - v;
    if (t < NB) {
        binptr[t] = excl;
        bincur[t] = excl;
    }
    if (t == 0) binptr[NB] = Etot;
}

__global__ __launch_bounds__(256) void binscatter_kernel(const int* __restrict__ ei,
                                                         int* __restrict__ bincur,
                                                         int2* __restrict__ binned,
                                                         int E, int Etot) {
    __shared__ int h[256];
    __shared__ int gb[256];
    int t = threadIdx.x;
    h[t] = 0;
    __syncthreads();
    int base = blockIdx.x * 4096;
    #pragma unroll
    for (int i = 0; i < 16; ++i) {
        int e = base + i * 256 + t;
        if (e < Etot) {
            int d = (e < E) ? ei[E + e] : (e - E);
            atomicAdd(&h[d >> BIN_SHIFT], 1);
        }
    }
    __syncthreads();
    int cnt = h[t];
    if (cnt) gb[t] = atomicAdd(&bincur[t], cnt);
    __syncthreads();
    h[t] = 0;
    __syncthreads();
    #pragma unroll
    for (int i = 0; i < 16; ++i) {
        int e = base + i * 256 + t;
        if (e < Etot) {
            int s, d;
            if (e < E) { s = ei[e]; d = ei[E + e]; }
            else       { s = e - E; d = e - E; }
            int b = d >> BIN_SHIFT;
            int pos = gb[b] + atomicAdd(&h[b], 1);
            binned[pos] = make_int2(s, d);
        }
    }
}

__global__ __launch_bounds__(256) void bincsr_kernel(const int2* __restrict__ binned,
                                                     const int* __restrict__ binptr,
                                                     int* __restrict__ row_ptr,
                                                     int* __restrict__ col,
                                                     int N, int Etot) {
    __shared__ int h[256];
    __shared__ int cur[256];
    __shared__ int wsum[4];
    int b = blockIdx.x;
    int t = threadIdx.x;
    int lo = b << BIN_SHIFT;
    h[t] = 0;
    __syncthreads();
    int ebeg = binptr[b], eend = binptr[b + 1];
    for (int i = ebeg + t; i < eend; i += 256) atomicAdd(&h[binned[i].y - lo], 1);
    __syncthreads();
    int v = h[t];
    int lane = t & 63, w = t >> 6;
    int x = v;
    #pragma unroll
    for (int o = 1; o < 64; o <<= 1) {
        int y = __shfl_up(x, o);
        if (lane >= o) x += y;
    }
    if (lane == 63) wsum[w] = x;
    __syncthreads();
    int off = 0;
    #pragma unroll
    for (int i = 0; i < 4; ++i) off += (i < w) ? wsum[i] : 0;
    int excl = ebeg + off + x - v;
    int node = lo + t;
    if (node < N) row_ptr[node] = excl;
    cur[t] = excl;
    if (b == 0 && t == 0) row_ptr[N] = Etot;
    __syncthreads();
    for (int i = ebeg + t; i < eend; i += 256) {
        int2 sd = binned[i];
        int pos = atomicAdd(&cur[sd.y - lo], 1);
        col[pos] = sd.x;
    }
}

// ---------------- MFMA GEMM: Yb[N,M](bf16) = (X*scale+shift)@W --------------
// 128x64 block tile, 4 waves, each wave 32 rows x 64 cols via 2x4 16x16x32
// MFMA accumulators. A,B staged in LDS as bf16 (row stride 40 shorts = 80B,
// keeps 16B frag alignment + 2-way-max bank aliasing).

__global__ __launch_bounds__(256) void mfma_gemm_kernel(
    const float* __restrict__ X, const float* __restrict__ W,
    unsigned short* __restrict__ Yb, int Nrows, int K, int M,
    const float* __restrict__ scale, const float* __restrict__ shift) {
    __shared__ __align__(16) unsigned short a_lds[128][40];
    __shared__ __align__(16) unsigned short b_lds[64][40];
    const int t = threadIdx.x;
    const int row0 = blockIdx.x * 128;
    const int c0 = blockIdx.y * 64;
    const int w = t >> 6, lane = t & 63;
    const int quad = lane >> 4, mrow = lane & 15;
    f32x4 acc[2][4] = {};
    for (int k0 = 0; k0 < K; k0 += 32) {
        // stage A: 128x32 f32 -> bf16 (4 float4 per thread)
        #pragma unroll
        for (int i = 0; i < 4; ++i) {
            int f = i * 256 + t;
            int r = f >> 3, kq = f & 7;
            int grow = row0 + r;
            float4 xv = make_float4(0.f, 0.f, 0.f, 0.f);
            if (grow < Nrows) xv = *(const float4*)(X + (size_t)grow * K + k0 + kq * 4);
            if (scale) {
                float4 sc = *(const float4*)(scale + k0 + kq * 4);
                float4 sh = *(const float4*)(shift + k0 + kq * 4);
                xv.x = fmaf(xv.x, sc.x, sh.x);
                xv.y = fmaf(xv.y, sc.y, sh.y);
                xv.z = fmaf(xv.z, sc.z, sh.z);
                xv.w = fmaf(xv.w, sc.w, sh.w);
            }
            ushort4 pk;
            pk.x = (unsigned short)f2bfbits(xv.x);
            pk.y = (unsigned short)f2bfbits(xv.y);
            pk.z = (unsigned short)f2bfbits(xv.z);
            pk.w = (unsigned short)f2bfbits(xv.w);
            *(ushort4*)&a_lds[r][kq * 4] = pk;
        }
        // stage B: 32x64 f32 -> bf16 transposed to [n][k] (2 float4 per thread)
        #pragma unroll
        for (int i = 0; i < 2; ++i) {
            int f = i * 256 + t;
            int kr = f >> 4, cq = f & 15;
            float4 wv = *(const float4*)(W + (size_t)(k0 + kr) * M + c0 + cq * 4);
            b_lds[cq * 4 + 0][kr] = (unsigned short)f2bfbits(wv.x);
            b_lds[cq * 4 + 1][kr] = (unsigned short)f2bfbits(wv.y);
            b_lds[cq * 4 + 2][kr] = (unsigned short)f2bfbits(wv.z);
            b_lds[cq * 4 + 3][kr] = (unsigned short)f2bfbits(wv.w);
        }
        __syncthreads();
        bf16x8 a0 = *(const bf16x8*)&a_lds[w * 32 + mrow][quad * 8];
        bf16x8 a1 = *(const bf16x8*)&a_lds[w * 32 + 16 + mrow][quad * 8];
        #pragma unroll
        for (int c = 0; c < 4; ++c) {
            bf16x8 bf = *(const bf16x8*)&b_lds[c * 16 + mrow][quad * 8];
            acc[0][c] = __builtin_amdgcn_mfma_f32_16x16x32_bf16(a0, bf, acc[0][c], 0, 0, 0);
            acc[1][c] = __builtin_amdgcn_mfma_f32_16x16x32_bf16(a1, bf, acc[1][c], 0, 0, 0);
        }
        __syncthreads();
    }
    // epilogue: C/D layout col=lane&15, row=quad*4+reg
    #pragma unroll
    for (int i = 0; i < 2; ++i) {
        #pragma unroll
        for (int c = 0; c < 4; ++c) {
            #pragma unroll
            for (int r = 0; r < 4; ++r) {
                int grow = row0 + w * 32 + i * 16 + quad * 4 + r;
                if (grow < Nrows)
                    Yb[(size_t)grow * M + c0 + c * 16 + mrow] =
                        (unsigned short)f2bfbits(acc[i][c][r]);
            }
        }
    }
}

// ---------------- attention coefficients + global ls-max ----------------

template <int H>
__global__ __launch_bounds__(256) void attn_coef_kernel(
    const unsigned short* __restrict__ hb, const float* __restrict__ as_,
    const float* __restrict__ ad_, float* __restrict__ ls,
    float* __restrict__ ld, unsigned* __restrict__ lsmax_g, int N, int ngroups) {
    __shared__ unsigned lmax_lds[4];
    int t = threadIdx.x;
    if (t < 4) lmax_lds[t] = 0;
    __syncthreads();
    int lane = t & 63;
    float lmax = -3.0e38f;
    for (int g = blockIdx.x; g < ngroups; g += gridDim.x) {
        int n = g * 4 + (t >> 6);
        if (n >= N) continue;
        if (H == 4) {
            uint2 w = *(const uint2*)(hb + (size_t)n * 256 + lane * 4);
            float h0 = bf_lo(w.x), h1 = bf_hi(w.x), h2 = bf_lo(w.y), h3 = bf_hi(w.y);
            int cg = lane * 4;
            float4 av = *(const float4*)(as_ + cg);
            float4 dv = *(const float4*)(ad_ + cg);
            float su = h0 * av.x + h1 * av.y + h2 * av.z + h3 * av.w;
            float sd = h0 * dv.x + h1 * dv.y + h2 * dv.z + h3 * dv.w;
            #pragma unroll
            for (int o = 1; o < 16; o <<= 1) {
                su += __shfl_xor(su, o);
                sd += __shfl_xor(sd, o);
            }
            if ((lane & 15) == 0) {
                int hd = lane >> 4;
                ls[(size_t)n * 4 + hd] = su;
                ld[(size_t)n * 4 + hd] = sd;
            }
            lmax = fmaxf(lmax, su);
        } else {
            float hv = bf1(hb[(size_t)n * 64 + lane]);
            float su = hv * as_[lane];
            float sd = hv * ad_[lane];
            #pragma unroll
            for (int o = 32; o; o >>= 1) {
                su += __shfl_xor(su, o);
                sd += __shfl_xor(sd, o);
            }
            if (lane == 0) {
                ls[n] = su;
                ld[n] = sd;
            }
            lmax = fmaxf(lmax, su);
        }
    }
    unsigned key = fenc(lmax);
    if (H == 4) {
        if ((lane & 15) == 0) atomicMax(&lmax_lds[lane >> 4], key);
    } else {
        if (lane == 0) atomicMax(&lmax_lds[0], key);
    }
    __syncthreads();
    if (t < H) atomicMax(&lsmax_g[t], lmax_lds[t]);
}

// ---------------- layer-1/2 aggregation: one wave per node, unroll x8 -------

__global__ __launch_bounds__(256) void agg4_kernel(
    const unsigned short* __restrict__ hb, const float* __restrict__ ls,
    const float* __restrict__ ld, const int* __restrict__ row_ptr,
    const int* __restrict__ col, const float* __restrict__ bias,
    const unsigned* __restrict__ lsmax_g, float* __restrict__ out, int N) {
    int lane = threadIdx.x & 63;
    int n = blockIdx.x * 4 + (threadIdx.x >> 6);
    if (n >= N) return;
    int beg = row_ptr[n], end = row_ptr[n + 1];
    const int hd = lane >> 4;
    float4 ldn = *(const float4*)(ld + (size_t)n * 4);
    float ldn_h = (hd == 0) ? ldn.x : (hd == 1) ? ldn.y : (hd == 2) ? ldn.z : ldn.w;
    float m_h = fmaxf(0.f, ldn_h + fdec(lsmax_g[hd]));
    const int c0 = lane * 4;
    float psum = 0.f;
    float a0 = 0.f, a1 = 0.f, a2 = 0.f, a3 = 0.f;
    for (int base = beg; base < end; base += 64) {
        int el = base + lane;
        int s_r = (el < end) ? col[el] : 0;
        int cnt = min(64, end - base);
        int j = 0;
        for (; j + 8 <= cnt; j += 8) {
            int s[8];
            float l[8];
            uint2 w[8];
            #pragma unroll
            for (int q = 0; q < 8; ++q) s[q] = __shfl(s_r, j + q);
            #pragma unroll
            for (int q = 0; q < 8; ++q) l[q] = ls[(size_t)s[q] * 4 + hd];
            #pragma unroll
            for (int q = 0; q < 8; ++q) w[q] = *(const uint2*)(hb + (size_t)s[q] * 256 + c0);
            #pragma unroll
            for (int q = 0; q < 8; ++q) {
                float g = l[q] + ldn_h;
                g = fmaxf(g, 0.2f * g);
                float p = __expf(g - m_h);
                psum += p;
                a0 = fmaf(p, bf_lo(w[q].x), a0);
                a1 = fmaf(p, bf_hi(w[q].x), a1);
                a2 = fmaf(p, bf_lo(w[q].y), a2);
                a3 = fmaf(p, bf_hi(w[q].y), a3);
            }
        }
        for (; j < cnt; ++j) {
            int sj = __shfl(s_r, j);
            float lv = ls[(size_t)sj * 4 + hd];
            float gg = lv + ldn_h;
            gg = fmaxf(gg, 0.2f * gg);
            float pv = __expf(gg - m_h);
            psum += pv;
            uint2 w = *(const uint2*)(hb + (size_t)sj * 256 + c0);
            a0 = fmaf(pv, bf_lo(w.x), a0);
            a1 = fmaf(pv, bf_hi(w.x), a1);
            a2 = fmaf(pv, bf_lo(w.y), a2);
            a3 = fmaf(pv, bf_hi(w.y), a3);
        }
    }
    float inv = 1.f / (psum + 1e-16f);
    float4 bv = *(const float4*)(bias + c0);
    float4 o;
    o.x = fmaf(a0, inv, bv.x);
    o.y = fmaf(a1, inv, bv.y);
    o.z = fmaf(a2, inv, bv.z);
    o.w = fmaf(a3, inv, bv.w);
    o.x = (o.x > 0.f) ? o.x : expm1f(o.x);
    o.y = (o.y > 0.f) ? o.y : expm1f(o.y);
    o.z = (o.z > 0.f) ? o.z : expm1f(o.z);
    o.w = (o.w > 0.f) ? o.w : expm1f(o.w);
    *(float4*)(out + (size_t)n * 256 + c0) = o;
}

// ---------------- layer-3 aggregation (H=1): lane-parallel ------------------

__global__ __launch_bounds__(256) void agg3_kernel(
    const unsigned short* __restrict__ hb, const float* __restrict__ ls,
    const float* __restrict__ ld, const int* __restrict__ row_ptr,
    const int* __restrict__ col, const float* __restrict__ bias,
    const float* __restrict__ fcW, float* __restrict__ up, float* __restrict__ vp,
    const unsigned* __restrict__ lsmax_g, int N) {
    int lane = threadIdx.x & 63;
    int n = blockIdx.x * 4 + (threadIdx.x >> 6);
    if (n >= N) return;
    int beg = row_ptr[n], end = row_ptr[n + 1];
    float ldn = ld[n];
    float m_h = fmaxf(0.f, ldn + fdec(lsmax_g[0]));
    int g = lane >> 4;    // edge group 0..3
    int li = lane & 15;   // channel quad 0..15
    float psum = 0.f;
    float a0 = 0.f, a1 = 0.f, a2 = 0.f, a3 = 0.f;
    for (int j = beg + g; j < end; j += 4) {
        int s = col[j];
        float lg = ls[s] + ldn;
        lg = fmaxf(lg, 0.2f * lg);
        float pv = __expf(lg - m_h);
        psum += pv;
        uint2 w = *(const uint2*)(hb + (size_t)s * 64 + li * 4);
        a0 = fmaf(pv, bf_lo(w.x), a0);
        a1 = fmaf(pv, bf_hi(w.x), a1);
        a2 = fmaf(pv, bf_lo(w.y), a2);
        a3 = fmaf(pv, bf_hi(w.y), a3);
    }
    #pragma unroll
    for (int o = 16; o <= 32; o <<= 1) {
        psum += __shfl_xor(psum, o);
        a0 += __shfl_xor(a0, o);
        a1 += __shfl_xor(a1, o);
        a2 += __shfl_xor(a2, o);
        a3 += __shfl_xor(a3, o);
    }
    float inv = 1.f / (psum + 1e-16f);
    int c = li * 4;
    float v0 = fmaf(a0, inv, bias[c + 0]);
    float v1 = fmaf(a1, inv, bias[c + 1]);
    float v2 = fmaf(a2, inv, bias[c + 2]);
    float v3 = fmaf(a3, inv, bias[c + 3]);
    float pu = v0 * fcW[c] + v1 * fcW[c + 1] + v2 * fcW[c + 2] + v3 * fcW[c + 3];
    float pv2 = v0 * fcW[64 + c] + v1 * fcW[64 + c + 1] + v2 * fcW[64 + c + 2] +
                v3 * fcW[64 + c + 3];
    #pragma unroll
    for (int o = 1; o <= 8; o <<= 1) {
        pu += __shfl_xor(pu, o);
        pv2 += __shfl_xor(pv2, o);
    }
    if (lane == 0) {
        up[n] = pu;
        vp[n] = pv2;
    }
}

// ---------------- BN stats + finalize ----------------

__global__ __launch_bounds__(256) void bn_stats_kernel(const float* __restrict__ y,
                                                       float* __restrict__ sums,
                                                       int N) {
    int c = threadIdx.x;
    int r0 = blockIdx.x * 128;
    int rend = min(r0 + 128, N);
    float s = 0.f, s2 = 0.f;
    for (int r = r0; r < rend; ++r) {
        float v = y[(size_t)r * 256 + c];
        s += v;
        s2 += v * v;
    }
    atomicAdd(&sums[c], s);
    atomicAdd(&sums[256 + c], s2);
}

__global__ void bn_finalize_kernel(const float* __restrict__ sums,
                                   const float* __restrict__ g,
                                   const float* __restrict__ b,
                                   float* __restrict__ scale,
                                   float* __restrict__ shift, int N) {
    int c = threadIdx.x;
    float invN = 1.f / (float)N;
    float mu = sums[c] * invN;
    float var = sums[256 + c] * invN - mu * mu;
    float sc = g[c] * rsqrtf(var + 1e-5f);
    scale[c] = sc;
    shift[c] = b[c] - mu * sc;
}

// ---------------- final edge kernel prep + output ----------------

__global__ void prep_kernel(const float* __restrict__ mlpW2,
                            const float* __restrict__ mlpb2,
                            const float* __restrict__ fcW,
                            const float* __restrict__ fcb,
                            float* __restrict__ w2f, float* __restrict__ c2) {
    int j = threadIdx.x;  // 64
    float s = 0.f;
    for (int k = 0; k < 64; ++k) s += mlpW2[j * 64 + k] * fcW[128 + k];
    w2f[j] = s;
    if (j == 0) {
        float c = fcb[0];
        for (int k = 0; k < 64; ++k) c += mlpb2[k] * fcW[128 + k];
        c2[0] = c;
    }
}

// 4 edges per thread; W1 row read from LDS once per j, reused across 4 edges.
__global__ __launch_bounds__(256) void edge_out_kernel(
    const int* __restrict__ ei, const float* __restrict__ ea,
    const float* __restrict__ W1, const float* __restrict__ b1,
    const float* __restrict__ w2f, const float* __restrict__ c2p,
    const float* __restrict__ u, const float* __restrict__ v,
    float* __restrict__ out, int E) {
    __shared__ __align__(16) float W1T[64][16];
    __shared__ float w2fl[64];
    __shared__ float b1l[64];
    int t = threadIdx.x;
    for (int p = t; p < 1024; p += 256) {
        int i = p >> 6, j = p & 63;
        W1T[j][i] = W1[i * 64 + j];
    }
    if (t < 64) {
        w2fl[t] = w2f[t];
        b1l[t] = b1[t];
    }
    __syncthreads();
    int base = blockIdx.x * 1024;
    float eav[4][16];
    int sidx[4], didx[4];
    bool ok[4];
    #pragma unroll
    for (int k = 0; k < 4; ++k) {
        int e = base + k * 256 + t;
        ok[k] = e < E;
        int ec = ok[k] ? e : 0;
        sidx[k] = ei[ec];
        didx[k] = ei[E + ec];
        const float4* ear = (const float4*)(ea + (size_t)ec * 16);
        float4 q0 = ear[0], q1 = ear[1], q2 = ear[2], q3 = ear[3];
        eav[k][0] = q0.x;  eav[k][1] = q0.y;  eav[k][2] = q0.z;  eav[k][3] = q0.w;
        eav[k][4] = q1.x;  eav[k][5] = q1.y;  eav[k][6] = q1.z;  eav[k][7] = q1.w;
        eav[k][8] = q2.x;  eav[k][9] = q2.y;  eav[k][10] = q2.z; eav[k][11] = q2.w;
        eav[k][12] = q3.x; eav[k][13] = q3.y; eav[k][14] = q3.z; eav[k][15] = q3.w;
    }
    float acc[4] = {0.f, 0.f, 0.f, 0.f};
    #pragma unroll 4
    for (int j = 0; j < 64; ++j) {
        const float4* wr = (const float4*)&W1T[j][0];
        float4 w0 = wr[0], w1 = wr[1], w2 = wr[2], w3 = wr[3];
        float wrow[16] = {w0.x, w0.y, w0.z, w0.w, w1.x, w1.y, w1.z, w1.w,
                          w2.x, w2.y, w2.z, w2.w, w3.x, w3.y, w3.z, w3.w};
        float bj = b1l[j], wj = w2fl[j];
        #pragma unroll
        for (int k = 0; k < 4; ++k) {
            float s = bj;
            #pragma unroll
            for (int q = 0; q < 16; ++q) s = fmaf(eav[k][q], wrow[q], s);
            s = fmaxf(s, 0.f);
            acc[k] = fmaf(s, wj, acc[k]);
        }
    }
    float cc = c2p[0];
    #pragma unroll
    for (int k = 0; k < 4; ++k) {
        if (ok[k]) {
            int e = base + k * 256 + t;
            out[e] = u[sidx[k]] + v[didx[k]] + acc[k] + cc;
        }
    }
}

// ---------------- orchestration ----------------

extern "C" void kernel_launch(void* const* d_in, const int* in_sizes, int n_in,
                              void* d_out, int out_size, void* d_ws, size_t ws_size,
                              hipStream_t stream) {
    const float* x     = (const float*)d_in[0];
    const int*   ei    = (const int*)d_in[1];
    const float* ea    = (const float*)d_in[2];
    const float* W1    = (const float*)d_in[3];
    const float* a1s   = (const float*)d_in[4];
    const float* a1d   = (const float*)d_in[5];
    const float* b1    = (const float*)d_in[6];
    const float* W2    = (const float*)d_in[7];
    const float* a2s   = (const float*)d_in[8];
    const float* a2d   = (const float*)d_in[9];
    const float* b2    = (const float*)d_in[10];
    const float* W3    = (const float*)d_in[11];
    const float* a3s   = (const float*)d_in[12];
    const float* a3d   = (const float*)d_in[13];
    const float* b3    = (const float*)d_in[14];
    const float* bn1g  = (const float*)d_in[15];
    const float* bn1b  = (const float*)d_in[16];
    const float* bn2g  = (const float*)d_in[17];
    const float* bn2b  = (const float*)d_in[18];
    const float* mlpW1 = (const float*)d_in[19];
    const float* mlpb1 = (const float*)d_in[20];
    const float* mlpW2 = (const float*)d_in[21];
    const float* mlpb2 = (const float*)d_in[22];
    const float* fcW   = (const float*)d_in[23];
    const float* fcb   = (const float*)d_in[24];
    float* out = (float*)d_out;

    const int N = in_sizes[0] / FIN;     // 50000
    const int E = in_sizes[1] / 2;       // 1600000
    const int Etot = E + N;
    const int NB = (N + 255) >> BIN_SHIFT;  // 196

    // workspace layout
    char* wsb = (char*)d_ws;
    size_t off = 0;
    auto alloc = [&](size_t bytes) {
        void* p = wsb + off;
        off += (bytes + 63) & ~(size_t)63;
        return p;
    };
    unsigned short* hAb = (unsigned short*)alloc((size_t)N * 256 * 2);
    float* hB  = (float*)alloc((size_t)N * 256 * 4);
    unsigned short* h3b = (unsigned short*)alloc((size_t)N * 64 * 2);
    float* lsb = (float*)alloc((size_t)N * 4 * 4);
    float* ldb = (float*)alloc((size_t)N * 4 * 4);
    int* row_ptr = (int*)alloc((size_t)(N + 1) * 4);
    int* colb    = (int*)alloc((size_t)Etot * 4);
    int2* binned = (int2*)alloc((size_t)Etot * 8);
    int* bincnt  = (int*)alloc(256 * 4 + 12 * 4);  // + lsmax[3][4] zero-init
    unsigned* lsmax1 = (unsigned*)(bincnt + 256);
    unsigned* lsmax2 = lsmax1 + 4;
    unsigned* lsmax3 = lsmax1 + 8;
    int* binptr  = (int*)alloc((size_t)(NB + 1) * 4);
    int* bincur  = (int*)alloc((size_t)NB * 4);
    float* bnsum   = (float*)alloc(512 * 4);
    float* bnscale = (float*)alloc(256 * 4);
    float* bnshift = (float*)alloc(256 * 4);
    float* ub  = (float*)alloc((size_t)N * 4);
    float* vb  = (float*)alloc((size_t)N * 4);
    float* w2f = (float*)alloc(64 * 4);
    float* c2  = (float*)alloc(16 * 4);
    (void)ws_size; (void)n_in; (void)out_size;

    const int nb4 = (N + 3) / 4;
    const int nch = (Etot + 4095) / 4096;

    // ---- binned CSR build ----
    hipMemsetAsync(bincnt, 0, (256 + 12) * sizeof(int), stream);
    bincount_kernel<<<nch, 256, 0, stream>>>(ei, bincnt, E, Etot);
    scanbins_kernel<<<1, 256, 0, stream>>>(bincnt, binptr, bincur, NB, Etot);
    binscatter_kernel<<<nch, 256, 0, stream>>>(ei, bincur, binned, E, Etot);
    bincsr_kernel<<<NB, 256, 0, stream>>>(binned, binptr, row_ptr, colb, N, Etot);

    dim3 ggrid((N + 127) / 128, 4);
    dim3 ggrid3((N + 127) / 128, 1);

    // ---- layer 1 ----
    mfma_gemm_kernel<<<ggrid, 256, 0, stream>>>(x, W1, hAb, N, 128, 256, nullptr, nullptr);
    attn_coef_kernel<4><<<2048, 256, 0, stream>>>(hAb, a1s, a1d, lsb, ldb, lsmax1, N, nb4);
    agg4_kernel<<<nb4, 256, 0, stream>>>(hAb, lsb, ldb, row_ptr, colb, b1, lsmax1, hB, N);
    hipMemsetAsync(bnsum, 0, 512 * sizeof(float), stream);
    bn_stats_kernel<<<(N + 127) / 128, 256, 0, stream>>>(hB, bnsum, N);
    bn_finalize_kernel<<<1, 256, 0, stream>>>(bnsum, bn1g, bn1b, bnscale, bnshift, N);

    // ---- layer 2 ----
    mfma_gemm_kernel<<<ggrid, 256, 0, stream>>>(hB, W2, hAb, N, 256, 256, bnscale, bnshift);
    attn_coef_kernel<4><<<2048, 256, 0, stream>>>(hAb, a2s, a2d, lsb, ldb, lsmax2, N, nb4);
    agg4_kernel<<<nb4, 256, 0, stream>>>(hAb, lsb, ldb, row_ptr, colb, b2, lsmax2, hB, N);
    hipMemsetAsync(bnsum, 0, 512 * sizeof(float), stream);
    bn_stats_kernel<<<(N + 127) / 128, 256, 0, stream>>>(hB, bnsum, N);
    bn_finalize_kernel<<<1, 256, 0, stream>>>(bnsum, bn2g, bn2b, bnscale, bnshift, N);

    // ---- layer 3 ----
    mfma_gemm_kernel<<<ggrid3, 256, 0, stream>>>(hB, W3, h3b, N, 256, 64, bnscale, bnshift);
    attn_coef_kernel<1><<<2048, 256, 0, stream>>>(h3b, a3s, a3d, lsb, ldb, lsmax3, N, nb4);
    agg3_kernel<<<nb4, 256, 0, stream>>>(h3b, lsb, ldb, row_ptr, colb, b3,
                                         fcW, ub, vb, lsmax3, N);

    // ---- edge output ----
    prep_kernel<<<1, 64, 0, stream>>>(mlpW2, mlpb2, fcW, fcb, w2f, c2);
    edge_out_kernel<<<(E + 1023) / 1024, 256, 0, stream>>>(ei, ea, mlpW1, mlpb1, w2f, c2,
                                                           ub, vb, out, E);
}

// Round 7
// 784.820 us; speedup vs baseline: 1.7145x; 1.1034x over previous
//
#include <hip/hip_runtime.h>
#include <hip/hip_fp16.h>
#include <math.h>

// ---------------------------------------------------------------------------
// EdgeGAT R7: fusion pass.
//  - attn_coef fused into MFMA GEMM epilogue (ls/ld from f32 acc regs).
//  - bn_stats fused into agg (grid-strided, LDS channel sums, 1 atomic/ch/blk).
//  - bn_finalize folded into consumer GEMM; prep folded into edge_out.
//  - h stored f16 (not bf16): same bytes, 8x mantissa precision, f16 MFMA.
//  - 12 dispatches total (was 26).
// ---------------------------------------------------------------------------

#define FIN 128
#define HID 64
#define BIN_SHIFT 8   // 256 nodes per bin; requires N <= 65536

typedef _Float16 f16x8 __attribute__((ext_vector_type(8)));
typedef float f32x4 __attribute__((ext_vector_type(4)));

__device__ __forceinline__ unsigned short f2hbits(float f) {
    __half h = __float2half(f);
    return *reinterpret_cast<unsigned short*>(&h);
}
__device__ __forceinline__ float2 hpair(unsigned w) {
    __half2 h = *reinterpret_cast<__half2*>(&w);
    return __half22float2(h);
}

// monotone float<->uint encoding for atomicMax on floats
__device__ __forceinline__ unsigned fenc(float f) {
    unsigned b = __float_as_uint(f);
    return (b & 0x80000000u) ? ~b : (b | 0x80000000u);
}
__device__ __forceinline__ float fdec(unsigned k) {
    unsigned b = (k & 0x80000000u) ? (k ^ 0x80000000u) : ~k;
    return __uint_as_float(b);
}

// ---------------- binned CSR build ----------------

__global__ __launch_bounds__(256) void bincount_kernel(const int* __restrict__ ei,
                                                       int* __restrict__ bincnt,
                                                       int E, int Etot) {
    __shared__ int h[256];
    int t = threadIdx.x;
    h[t] = 0;
    __syncthreads();
    int base = blockIdx.x * 4096;
    #pragma unroll
    for (int i = 0; i < 16; ++i) {
        int e = base + i * 256 + t;
        if (e < Etot) {
            int d = (e < E) ? ei[E + e] : (e - E);
            atomicAdd(&h[d >> BIN_SHIFT], 1);
        }
    }
    __syncthreads();
    if (h[t]) atomicAdd(&bincnt[t], h[t]);
}

__global__ void scanbins_kernel(const int* __restrict__ bincnt, int* __restrict__ binptr,
                                int* __restrict__ bincur, int NB, int Etot) {
    __shared__ int buf[256];
    int t = threadIdx.x;  // 256
    int v = (t < NB) ? bincnt[t] : 0;
    buf[t] = v;
    __syncthreads();
    for (int o = 1; o < 256; o <<= 1) {
        int y = (t >= o) ? buf[t - o] : 0;
        __syncthreads();
        buf[t] += y;
        __syncthreads();
    }
    int excl = buf[t] - v;
    if (t < NB) {
        binptr[t] = excl;
        bincur[t] = excl;
    }
    if (t == 0) binptr[NB] = Etot;
}

__global__ __launch_bounds__(256) void binscatter_kernel(const int* __restrict__ ei,
                                                         int* __restrict__ bincur,
                                                         int2* __restrict__ binned,
                                                         int E, int Etot) {
    __shared__ int h[256];
    __shared__ int gb[256];
    int t = threadIdx.x;
    h[t] = 0;
    __syncthreads();
    int base = blockIdx.x * 4096;
    #pragma unroll
    for (int i = 0; i < 16; ++i) {
        int e = base + i * 256 + t;
        if (e < Etot) {
            int d = (e < E) ? ei[E + e] : (e - E);
            atomicAdd(&h[d >> BIN_SHIFT], 1);
        }
    }
    __syncthreads();
    int cnt = h[t];
    if (cnt) gb[t] = atomicAdd(&bincur[t], cnt);
    __syncthreads();
    h[t] = 0;
    __syncthreads();
    #pragma unroll
    for (int i = 0; i < 16; ++i) {
        int e = base + i * 256 + t;
        if (e < Etot) {
            int s, d;
            if (e < E) { s = ei[e]; d = ei[E + e]; }
            else       { s = e - E; d = e - E; }
            int b = d >> BIN_SHIFT;
            int pos = gb[b] + atomicAdd(&h[b], 1);
            binned[pos] = make_int2(s, d);
        }
    }
}

__global__ __launch_bounds__(256) void bincsr_kernel(const int2* __restrict__ binned,
                                                     const int* __restrict__ binptr,
                                                     int* __restrict__ row_ptr,
                                                     int* __restrict__ col,
                                                     int N, int Etot) {
    __shared__ int h[256];
    __shared__ int cur[256];
    __shared__ int wsum[4];
    int b = blockIdx.x;
    int t = threadIdx.x;
    int lo = b << BIN_SHIFT;
    h[t] = 0;
    __syncthreads();
    int ebeg = binptr[b], eend = binptr[b + 1];
    for (int i = ebeg + t; i < eend; i += 256) atomicAdd(&h[binned[i].y - lo], 1);
    __syncthreads();
    int v = h[t];
    int lane = t & 63, w = t >> 6;
    int x = v;
    #pragma unroll
    for (int o = 1; o < 64; o <<= 1) {
        int y = __shfl_up(x, o);
        if (lane >= o) x += y;
    }
    if (lane == 63) wsum[w] = x;
    __syncthreads();
    int off = 0;
    #pragma unroll
    for (int i = 0; i < 4; ++i) off += (i < w) ? wsum[i] : 0;
    int excl = ebeg + off + x - v;
    int node = lo + t;
    if (node < N) row_ptr[node] = excl;
    cur[t] = excl;
    if (b == 0 && t == 0) row_ptr[N] = Etot;
    __syncthreads();
    for (int i = ebeg + t; i < eend; i += 256) {
        int2 sd = binned[i];
        int pos = atomicAdd(&cur[sd.y - lo], 1);
        col[pos] = sd.x;
    }
}

// ---------------- MFMA GEMM (f16) + fused BN-from-sums + fused attn ---------
// Yh[N,M](f16) = BN(X)@W. BN scale/shift derived per-block from raw sums.
// Epilogue computes ls/ld for this block's rows (head = blockIdx.y) from the
// f32 accumulators and atomicMax's the global per-head ls-max.

__global__ __launch_bounds__(256) void mfma_gemm_kernel(
    const float* __restrict__ X, const float* __restrict__ W,
    unsigned short* __restrict__ Yh, int Nrows, int K, int M,
    const float* __restrict__ bnsum, const float* __restrict__ bng,
    const float* __restrict__ bnb, float invN,
    const float* __restrict__ as_, const float* __restrict__ ad_,
    float* __restrict__ ls, float* __restrict__ ld,
    unsigned* __restrict__ lsmax_g, int H) {
    __shared__ __align__(16) unsigned short a_lds[128][40];
    __shared__ __align__(16) unsigned short b_lds[64][40];
    __shared__ __align__(16) float scale_l[256];
    __shared__ __align__(16) float shift_l[256];
    __shared__ unsigned lmax_l;
    const int t = threadIdx.x;
    const int row0 = blockIdx.x * 128;
    const int by = blockIdx.y;
    const int c0 = by * 64;
    const int w = t >> 6, lane = t & 63;
    const int quad = lane >> 4, mrow = lane & 15;
    if (t == 0) lmax_l = 0;
    if (bnsum && t < 256) {
        float mu = bnsum[t] * invN;
        float var = bnsum[256 + t] * invN - mu * mu;
        float sc = bng[t] * rsqrtf(var + 1e-5f);
        scale_l[t] = sc;
        shift_l[t] = bnb[t] - mu * sc;
    }
    __syncthreads();
    f32x4 acc[2][4] = {};
    for (int k0 = 0; k0 < K; k0 += 32) {
        #pragma unroll
        for (int i = 0; i < 4; ++i) {
            int f = i * 256 + t;
            int r = f >> 3, kq = f & 7;
            int grow = row0 + r;
            float4 xv = make_float4(0.f, 0.f, 0.f, 0.f);
            if (grow < Nrows) xv = *(const float4*)(X + (size_t)grow * K + k0 + kq * 4);
            if (bnsum) {
                float4 sc = *(const float4*)&scale_l[k0 + kq * 4];
                float4 sh = *(const float4*)&shift_l[k0 + kq * 4];
                xv.x = fmaf(xv.x, sc.x, sh.x);
                xv.y = fmaf(xv.y, sc.y, sh.y);
                xv.z = fmaf(xv.z, sc.z, sh.z);
                xv.w = fmaf(xv.w, sc.w, sh.w);
            }
            ushort4 pk;
            pk.x = f2hbits(xv.x);
            pk.y = f2hbits(xv.y);
            pk.z = f2hbits(xv.z);
            pk.w = f2hbits(xv.w);
            *(ushort4*)&a_lds[r][kq * 4] = pk;
        }
        #pragma unroll
        for (int i = 0; i < 2; ++i) {
            int f = i * 256 + t;
            int kr = f >> 4, cq = f & 15;
            float4 wv = *(const float4*)(W + (size_t)(k0 + kr) * M + c0 + cq * 4);
            b_lds[cq * 4 + 0][kr] = f2hbits(wv.x);
            b_lds[cq * 4 + 1][kr] = f2hbits(wv.y);
            b_lds[cq * 4 + 2][kr] = f2hbits(wv.z);
            b_lds[cq * 4 + 3][kr] = f2hbits(wv.w);
        }
        __syncthreads();
        f16x8 a0 = *(const f16x8*)&a_lds[w * 32 + mrow][quad * 8];
        f16x8 a1 = *(const f16x8*)&a_lds[w * 32 + 16 + mrow][quad * 8];
        #pragma unroll
        for (int c = 0; c < 4; ++c) {
            f16x8 bf = *(const f16x8*)&b_lds[c * 16 + mrow][quad * 8];
            acc[0][c] = __builtin_amdgcn_mfma_f32_16x16x32_f16(a0, bf, acc[0][c], 0, 0, 0);
            acc[1][c] = __builtin_amdgcn_mfma_f32_16x16x32_f16(a1, bf, acc[1][c], 0, 0, 0);
        }
        __syncthreads();
    }
    // C/D: col = c*16+mrow, row = w*32 + i*16 + quad*4 + r
    #pragma unroll
    for (int i = 0; i < 2; ++i) {
        #pragma unroll
        for (int c = 0; c < 4; ++c) {
            #pragma unroll
            for (int r = 0; r < 4; ++r) {
                int grow = row0 + w * 32 + i * 16 + quad * 4 + r;
                if (grow < Nrows)
                    Yh[(size_t)grow * M + c0 + c * 16 + mrow] = f2hbits(acc[i][c][r]);
            }
        }
    }
    // fused attn: ls/ld for this head's 64 cols
    float asv[4], adv[4];
    #pragma unroll
    for (int c = 0; c < 4; ++c) {
        asv[c] = as_[by * 64 + c * 16 + mrow];
        adv[c] = ad_[by * 64 + c * 16 + mrow];
    }
    float lmax = -3.0e38f;
    #pragma unroll
    for (int i = 0; i < 2; ++i) {
        #pragma unroll
        for (int r = 0; r < 4; ++r) {
            float ps = 0.f, pd = 0.f;
            #pragma unroll
            for (int c = 0; c < 4; ++c) {
                ps = fmaf(acc[i][c][r], asv[c], ps);
                pd = fmaf(acc[i][c][r], adv[c], pd);
            }
            #pragma unroll
            for (int o = 1; o <= 8; o <<= 1) {
                ps += __shfl_xor(ps, o);
                pd += __shfl_xor(pd, o);
            }
            int grow = row0 + w * 32 + i * 16 + quad * 4 + r;
            if (mrow == 0 && grow < Nrows) {
                ls[(size_t)grow * H + by] = ps;
                ld[(size_t)grow * H + by] = pd;
                lmax = fmaxf(lmax, ps);
            }
        }
    }
    if (mrow == 0) atomicMax(&lmax_l, fenc(lmax));
    __syncthreads();
    if (t == 0) atomicMax(&lsmax_g[by], lmax_l);
}

// ---------------- layers 1/2 aggregation + fused BN stats -------------------
// Grid-strided (2048 blocks), one wave per node, unroll x4. Per-wave LDS
// channel sums; one atomicAdd per channel per block at the end.

__global__ __launch_bounds__(256) void agg_bn_kernel(
    const unsigned short* __restrict__ hb, const float* __restrict__ ls,
    const float* __restrict__ ld, const int* __restrict__ row_ptr,
    const int* __restrict__ col, const float* __restrict__ bias,
    const unsigned* __restrict__ lsmax_g, float* __restrict__ out,
    float* __restrict__ bnsum, int N, int ngroups) {
    __shared__ float accs[4][256];
    __shared__ float accq[4][256];
    int t = threadIdx.x;
    int w = t >> 6, lane = t & 63;
    const int hd = lane >> 4;
    const int c0 = lane * 4;
    #pragma unroll
    for (int i = 0; i < 4; ++i) {
        accs[w][c0 + i] = 0.f;
        accq[w][c0 + i] = 0.f;
    }
    float lsm = fdec(lsmax_g[hd]);
    for (int g = blockIdx.x; g < ngroups; g += gridDim.x) {
        int n = g * 4 + w;
        if (n >= N) continue;
        int beg = row_ptr[n], end = row_ptr[n + 1];
        float4 ldn = *(const float4*)(ld + (size_t)n * 4);
        float ldn_h = (hd == 0) ? ldn.x : (hd == 1) ? ldn.y : (hd == 2) ? ldn.z : ldn.w;
        float m_h = fmaxf(0.f, ldn_h + lsm);
        float psum = 0.f;
        float a0 = 0.f, a1 = 0.f, a2 = 0.f, a3 = 0.f;
        for (int base = beg; base < end; base += 64) {
            int el = base + lane;
            int s_r = (el < end) ? col[el] : 0;
            int cnt = min(64, end - base);
            int j = 0;
            for (; j + 4 <= cnt; j += 4) {
                int s0 = __shfl(s_r, j);
                int s1 = __shfl(s_r, j + 1);
                int s2 = __shfl(s_r, j + 2);
                int s3 = __shfl(s_r, j + 3);
                float l0 = ls[(size_t)s0 * 4 + hd];
                float l1 = ls[(size_t)s1 * 4 + hd];
                float l2 = ls[(size_t)s2 * 4 + hd];
                float l3 = ls[(size_t)s3 * 4 + hd];
                uint2 w0 = *(const uint2*)(hb + (size_t)s0 * 256 + c0);
                uint2 w1 = *(const uint2*)(hb + (size_t)s1 * 256 + c0);
                uint2 w2 = *(const uint2*)(hb + (size_t)s2 * 256 + c0);
                uint2 w3 = *(const uint2*)(hb + (size_t)s3 * 256 + c0);
                float g0 = l0 + ldn_h; g0 = fmaxf(g0, 0.2f * g0);
                float g1 = l1 + ldn_h; g1 = fmaxf(g1, 0.2f * g1);
                float g2 = l2 + ldn_h; g2 = fmaxf(g2, 0.2f * g2);
                float g3 = l3 + ldn_h; g3 = fmaxf(g3, 0.2f * g3);
                float p0 = __expf(g0 - m_h), p1 = __expf(g1 - m_h);
                float p2 = __expf(g2 - m_h), p3 = __expf(g3 - m_h);
                psum += (p0 + p1) + (p2 + p3);
                float2 f0a = hpair(w0.x), f0b = hpair(w0.y);
                float2 f1a = hpair(w1.x), f1b = hpair(w1.y);
                float2 f2a = hpair(w2.x), f2b = hpair(w2.y);
                float2 f3a = hpair(w3.x), f3b = hpair(w3.y);
                a0 = fmaf(p0, f0a.x, a0); a1 = fmaf(p0, f0a.y, a1);
                a2 = fmaf(p0, f0b.x, a2); a3 = fmaf(p0, f0b.y, a3);
                a0 = fmaf(p1, f1a.x, a0); a1 = fmaf(p1, f1a.y, a1);
                a2 = fmaf(p1, f1b.x, a2); a3 = fmaf(p1, f1b.y, a3);
                a0 = fmaf(p2, f2a.x, a0); a1 = fmaf(p2, f2a.y, a1);
                a2 = fmaf(p2, f2b.x, a2); a3 = fmaf(p2, f2b.y, a3);
                a0 = fmaf(p3, f3a.x, a0); a1 = fmaf(p3, f3a.y, a1);
                a2 = fmaf(p3, f3b.x, a2); a3 = fmaf(p3, f3b.y, a3);
            }
            for (; j < cnt; ++j) {
                int sj = __shfl(s_r, j);
                float lv = ls[(size_t)sj * 4 + hd];
                float gg = lv + ldn_h; gg = fmaxf(gg, 0.2f * gg);
                float pv = __expf(gg - m_h);
                psum += pv;
                uint2 wj = *(const uint2*)(hb + (size_t)sj * 256 + c0);
                float2 fa = hpair(wj.x), fb = hpair(wj.y);
                a0 = fmaf(pv, fa.x, a0); a1 = fmaf(pv, fa.y, a1);
                a2 = fmaf(pv, fb.x, a2); a3 = fmaf(pv, fb.y, a3);
            }
        }
        float inv = 1.f / (psum + 1e-16f);
        float4 bv = *(const float4*)(bias + c0);
        float4 o;
        o.x = fmaf(a0, inv, bv.x);
        o.y = fmaf(a1, inv, bv.y);
        o.z = fmaf(a2, inv, bv.z);
        o.w = fmaf(a3, inv, bv.w);
        o.x = (o.x > 0.f) ? o.x : expm1f(o.x);
        o.y = (o.y > 0.f) ? o.y : expm1f(o.y);
        o.z = (o.z > 0.f) ? o.z : expm1f(o.z);
        o.w = (o.w > 0.f) ? o.w : expm1f(o.w);
        *(float4*)(out + (size_t)n * 256 + c0) = o;
        accs[w][c0 + 0] += o.x; accq[w][c0 + 0] += o.x * o.x;
        accs[w][c0 + 1] += o.y; accq[w][c0 + 1] += o.y * o.y;
        accs[w][c0 + 2] += o.z; accq[w][c0 + 2] += o.z * o.z;
        accs[w][c0 + 3] += o.w; accq[w][c0 + 3] += o.w * o.w;
    }
    __syncthreads();
    float s = accs[0][t] + accs[1][t] + accs[2][t] + accs[3][t];
    float q = accq[0][t] + accq[1][t] + accq[2][t] + accq[3][t];
    atomicAdd(&bnsum[t], s);
    atomicAdd(&bnsum[256 + t], q);
}

// ---------------- layer-3 aggregation (H=1): lane-parallel ------------------

__global__ __launch_bounds__(256) void agg3_kernel(
    const unsigned short* __restrict__ hb, const float* __restrict__ ls,
    const float* __restrict__ ld, const int* __restrict__ row_ptr,
    const int* __restrict__ col, const float* __restrict__ bias,
    const float* __restrict__ fcW, float* __restrict__ up, float* __restrict__ vp,
    const unsigned* __restrict__ lsmax_g, int N) {
    int lane = threadIdx.x & 63;
    int n = blockIdx.x * 4 + (threadIdx.x >> 6);
    if (n >= N) return;
    int beg = row_ptr[n], end = row_ptr[n + 1];
    float ldn = ld[n];
    float m_h = fmaxf(0.f, ldn + fdec(lsmax_g[0]));
    int g = lane >> 4;    // edge group 0..3
    int li = lane & 15;   // channel quad 0..15
    float psum = 0.f;
    float a0 = 0.f, a1 = 0.f, a2 = 0.f, a3 = 0.f;
    for (int j = beg + g; j < end; j += 4) {
        int s = col[j];
        float lg = ls[s] + ldn;
        lg = fmaxf(lg, 0.2f * lg);
        float pv = __expf(lg - m_h);
        psum += pv;
        uint2 w = *(const uint2*)(hb + (size_t)s * 64 + li * 4);
        float2 fa = hpair(w.x), fb = hpair(w.y);
        a0 = fmaf(pv, fa.x, a0);
        a1 = fmaf(pv, fa.y, a1);
        a2 = fmaf(pv, fb.x, a2);
        a3 = fmaf(pv, fb.y, a3);
    }
    #pragma unroll
    for (int o = 16; o <= 32; o <<= 1) {
        psum += __shfl_xor(psum, o);
        a0 += __shfl_xor(a0, o);
        a1 += __shfl_xor(a1, o);
        a2 += __shfl_xor(a2, o);
        a3 += __shfl_xor(a3, o);
    }
    float inv = 1.f / (psum + 1e-16f);
    int c = li * 4;
    float v0 = fmaf(a0, inv, bias[c + 0]);
    float v1 = fmaf(a1, inv, bias[c + 1]);
    float v2 = fmaf(a2, inv, bias[c + 2]);
    float v3 = fmaf(a3, inv, bias[c + 3]);
    float pu = v0 * fcW[c] + v1 * fcW[c + 1] + v2 * fcW[c + 2] + v3 * fcW[c + 3];
    float pv2 = v0 * fcW[64 + c] + v1 * fcW[64 + c + 1] + v2 * fcW[64 + c + 2] +
                v3 * fcW[64 + c + 3];
    #pragma unroll
    for (int o = 1; o <= 8; o <<= 1) {
        pu += __shfl_xor(pu, o);
        pv2 += __shfl_xor(pv2, o);
    }
    if (lane == 0) {
        up[n] = pu;
        vp[n] = pv2;
    }
}

// ---------------- final edge output (prep folded in) ------------------------

__global__ __launch_bounds__(256) void edge_out_kernel(
    const int* __restrict__ ei, const float* __restrict__ ea,
    const float* __restrict__ W1, const float* __restrict__ b1,
    const float* __restrict__ mlpW2, const float* __restrict__ mlpb2,
    const float* __restrict__ fcW, const float* __restrict__ fcb,
    const float* __restrict__ u, const float* __restrict__ v,
    float* __restrict__ out, int E) {
    __shared__ __align__(16) float W1T[64][16];
    __shared__ float w2fl[64];
    __shared__ float b1l[64];
    __shared__ float c2l;
    int t = threadIdx.x;
    for (int p = t; p < 1024; p += 256) {
        int i = p >> 6, j = p & 63;
        W1T[j][i] = W1[i * 64 + j];
    }
    if (t < 64) {
        float s = 0.f;
        for (int k = 0; k < 64; ++k) s = fmaf(mlpW2[t * 64 + k], fcW[128 + k], s);
        w2fl[t] = s;
        b1l[t] = b1[t];
    }
    if (t == 0) {
        float c = fcb[0];
        for (int k = 0; k < 64; ++k) c = fmaf(mlpb2[k], fcW[128 + k], c);
        c2l = c;
    }
    __syncthreads();
    int base = blockIdx.x * 1024;
    float eav[4][16];
    int sidx[4], didx[4];
    bool ok[4];
    #pragma unroll
    for (int k = 0; k < 4; ++k) {
        int e = base + k * 256 + t;
        ok[k] = e < E;
        int ec = ok[k] ? e : 0;
        sidx[k] = ei[ec];
        didx[k] = ei[E + ec];
        const float4* ear = (const float4*)(ea + (size_t)ec * 16);
        float4 q0 = ear[0], q1 = ear[1], q2 = ear[2], q3 = ear[3];
        eav[k][0] = q0.x;  eav[k][1] = q0.y;  eav[k][2] = q0.z;  eav[k][3] = q0.w;
        eav[k][4] = q1.x;  eav[k][5] = q1.y;  eav[k][6] = q1.z;  eav[k][7] = q1.w;
        eav[k][8] = q2.x;  eav[k][9] = q2.y;  eav[k][10] = q2.z; eav[k][11] = q2.w;
        eav[k][12] = q3.x; eav[k][13] = q3.y; eav[k][14] = q3.z; eav[k][15] = q3.w;
    }
    float acc[4] = {0.f, 0.f, 0.f, 0.f};
    #pragma unroll 4
    for (int j = 0; j < 64; ++j) {
        const float4* wr = (const float4*)&W1T[j][0];
        float4 w0 = wr[0], w1 = wr[1], w2 = wr[2], w3 = wr[3];
        float wrow[16] = {w0.x, w0.y, w0.z, w0.w, w1.x, w1.y, w1.z, w1.w,
                          w2.x, w2.y, w2.z, w2.w, w3.x, w3.y, w3.z, w3.w};
        float bj = b1l[j], wj = w2fl[j];
        #pragma unroll
        for (int k = 0; k < 4; ++k) {
            float s = bj;
            #pragma unroll
            for (int q = 0; q < 16; ++q) s = fmaf(eav[k][q], wrow[q], s);
            s = fmaxf(s, 0.f);
            acc[k] = fmaf(s, wj, acc[k]);
        }
    }
    float cc = c2l;
    #pragma unroll
    for (int k = 0; k < 4; ++k) {
        if (ok[k]) {
            int e = base + k * 256 + t;
            out[e] = u[sidx[k]] + v[didx[k]] + acc[k] + cc;
        }
    }
}

// ---------------- orchestration ----------------

extern "C" void kernel_launch(void* const* d_in, const int* in_sizes, int n_in,
                              void* d_out, int out_size, void* d_ws, size_t ws_size,
                              hipStream_t stream) {
    const float* x     = (const float*)d_in[0];
    const int*   ei    = (const int*)d_in[1];
    const float* ea    = (const float*)d_in[2];
    const float* W1    = (const float*)d_in[3];
    const float* a1s   = (const float*)d_in[4];
    const float* a1d   = (const float*)d_in[5];
    const float* b1    = (const float*)d_in[6];
    const float* W2    = (const float*)d_in[7];
    const float* a2s   = (const float*)d_in[8];
    const float* a2d   = (const float*)d_in[9];
    const float* b2    = (const float*)d_in[10];
    const float* W3    = (const float*)d_in[11];
    const float* a3s   = (const float*)d_in[12];
    const float* a3d   = (const float*)d_in[13];
    const float* b3    = (const float*)d_in[14];
    const float* bn1g  = (const float*)d_in[15];
    const float* bn1b  = (const float*)d_in[16];
    const float* bn2g  = (const float*)d_in[17];
    const float* bn2b  = (const float*)d_in[18];
    const float* mlpW1 = (const float*)d_in[19];
    const float* mlpb1 = (const float*)d_in[20];
    const float* mlpW2 = (const float*)d_in[21];
    const float* mlpb2 = (const float*)d_in[22];
    const float* fcW   = (const float*)d_in[23];
    const float* fcb   = (const float*)d_in[24];
    float* out = (float*)d_out;

    const int N = in_sizes[0] / FIN;     // 50000
    const int E = in_sizes[1] / 2;       // 1600000
    const int Etot = E + N;
    const int NB = (N + 255) >> BIN_SHIFT;  // 196

    // workspace layout
    char* wsb = (char*)d_ws;
    size_t off = 0;
    auto alloc = [&](size_t bytes) {
        void* p = wsb + off;
        off += (bytes + 63) & ~(size_t)63;
        return p;
    };
    unsigned short* hAb = (unsigned short*)alloc((size_t)N * 256 * 2);  // f16 h
    float* hB  = (float*)alloc((size_t)N * 256 * 4);
    unsigned short* h3b = (unsigned short*)alloc((size_t)N * 64 * 2);   // f16 h3
    float* lsb = (float*)alloc((size_t)N * 4 * 4);
    float* ldb = (float*)alloc((size_t)N * 4 * 4);
    int* row_ptr = (int*)alloc((size_t)(N + 1) * 4);
    int* colb    = (int*)alloc((size_t)Etot * 4);
    int2* binned = (int2*)alloc((size_t)Etot * 8);
    // single contiguous zero-init region:
    // bincnt[256] | lsmax1[4] lsmax2[4] lsmax3[4] pad[4] | bnsumA[512] | bnsumB[512]
    int* zreg    = (int*)alloc((256 + 16 + 512 + 512) * 4);
    int* bincnt  = zreg;
    unsigned* lsmax1 = (unsigned*)(zreg + 256);
    unsigned* lsmax2 = lsmax1 + 4;
    unsigned* lsmax3 = lsmax1 + 8;
    float* bnsumA = (float*)(zreg + 256 + 16);
    float* bnsumB = bnsumA + 512;
    int* binptr  = (int*)alloc((size_t)(NB + 1) * 4);
    int* bincur  = (int*)alloc((size_t)NB * 4);
    float* ub  = (float*)alloc((size_t)N * 4);
    float* vb  = (float*)alloc((size_t)N * 4);
    (void)ws_size; (void)n_in; (void)out_size;

    const int nb4 = (N + 3) / 4;
    const int nch = (Etot + 4095) / 4096;
    const float invN = 1.f / (float)N;

    // ---- CSR build ----
    hipMemsetAsync(zreg, 0, (256 + 16 + 512 + 512) * sizeof(int), stream);
    bincount_kernel<<<nch, 256, 0, stream>>>(ei, bincnt, E, Etot);
    scanbins_kernel<<<1, 256, 0, stream>>>(bincnt, binptr, bincur, NB, Etot);
    binscatter_kernel<<<nch, 256, 0, stream>>>(ei, bincur, binned, E, Etot);
    bincsr_kernel<<<NB, 256, 0, stream>>>(binned, binptr, row_ptr, colb, N, Etot);

    dim3 ggrid((N + 127) / 128, 4);
    dim3 ggrid3((N + 127) / 128, 1);

    // ---- layer 1 ----
    mfma_gemm_kernel<<<ggrid, 256, 0, stream>>>(x, W1, hAb, N, 128, 256,
        nullptr, nullptr, nullptr, invN, a1s, a1d, lsb, ldb, lsmax1, 4);
    agg_bn_kernel<<<2048, 256, 0, stream>>>(hAb, lsb, ldb, row_ptr, colb, b1,
                                            lsmax1, hB, bnsumA, N, nb4);
    // ---- layer 2 ----
    mfma_gemm_kernel<<<ggrid, 256, 0, stream>>>(hB, W2, hAb, N, 256, 256,
        bnsumA, bn1g, bn1b, invN, a2s, a2d, lsb, ldb, lsmax2, 4);
    agg_bn_kernel<<<2048, 256, 0, stream>>>(hAb, lsb, ldb, row_ptr, colb, b2,
                                            lsmax2, hB, bnsumB, N, nb4);
    // ---- layer 3 ----
    mfma_gemm_kernel<<<ggrid3, 256, 0, stream>>>(hB, W3, h3b, N, 256, 64,
        bnsumB, bn2g, bn2b, invN, a3s, a3d, lsb, ldb, lsmax3, 1);
    agg3_kernel<<<nb4, 256, 0, stream>>>(h3b, lsb, ldb, row_ptr, colb, b3,
                                         fcW, ub, vb, lsmax3, N);
    // ---- edge output ----
    edge_out_kernel<<<(E + 1023) / 1024, 256, 0, stream>>>(
        ei, ea, mlpW1, mlpb1, mlpW2, mlpb2, fcW, fcb, ub, vb, out, E);
}